// Round 1
// baseline (449.635 us; speedup 1.0000x reference)
//
#include <hip/hip_runtime.h>
#include <hip/hip_bf16.h>
#include <math.h>

#define N_NODES 4096
#define NFEAT   1024
#define NHID    64
#define NHEADS  8
#define NCLASS  8
#define NBLOCKS 3
#define ALPHA   0.1f
#define MAXDEG  256

// ---------------------------------------------------------------------------
// K1: build padded CSR + dinv = 1/sqrt(degree) from dense int adjacency.
// One wave per row; ballot-compaction keeps neighbor order ascending
// (deterministic sums for graph-replay revalidation).
// ---------------------------------------------------------------------------
__global__ __launch_bounds__(64) void build_csr(const int* __restrict__ adj,
                                                int* __restrict__ csr,
                                                int* __restrict__ rowlen,
                                                float* __restrict__ dinv) {
    int row = blockIdx.x;
    int lane = threadIdx.x;
    const int* arow = adj + (size_t)row * N_NODES;
    int count = 0;
    for (int base = 0; base < N_NODES; base += 64) {
        int v = arow[base + lane];
        unsigned long long m = __ballot(v != 0);
        int prefix = __popcll(m & ((1ull << lane) - 1ull));
        if (v != 0) {
            int pos = count + prefix;
            if (pos < MAXDEG) csr[(size_t)row * MAXDEG + pos] = base + lane;
        }
        count += __popcll(m);
    }
    if (lane == 0) {
        rowlen[row] = count < MAXDEG ? count : MAXDEG;
        dinv[row] = 1.0f / sqrtf((float)count);   // every row has a self loop -> count >= 1
    }
}

// ---------------------------------------------------------------------------
// K2: tiled fp32 GEMM.  A:[M][K] row-major.  B viewed as [N/64][K][64]
// (W_heads is exactly [8][1024][64]; W_out [512][64] is the degenerate
// [1][512][64] case).  C:[M][ldc], block tile 64x64, BK=16, 4x4 microtile.
// ---------------------------------------------------------------------------
#define BM 64
#define BN 64
#define BK 16

__global__ __launch_bounds__(256) void gemm_tiled(const float* __restrict__ A,
                                                  const float* __restrict__ B,
                                                  float* __restrict__ C,
                                                  int K, int ldc) {
    __shared__ float As[BK][BM + 4];
    __shared__ float Bs[BK][BN + 4];
    int tid = threadIdx.x;
    int row0 = blockIdx.x * BM;
    int col0 = blockIdx.y * BN;

    int tr = (tid >> 4) << 2;       // 0..60
    int tc = (tid & 15) << 2;       // 0..60

    int am = tid >> 2;              // 0..63
    int ak = (tid & 3) << 2;        // 0,4,8,12
    int bc = tid & 63;              // 0..63
    int bk0 = tid >> 6;             // 0..3

    const float* Aptr = A + (size_t)(row0 + am) * K + ak;
    int head = (col0 + bc) >> 6;
    int j = (col0 + bc) & 63;
    const float* Bptr = B + (size_t)head * K * 64 + j;

    float acc[4][4] = {};

    for (int k0 = 0; k0 < K; k0 += BK) {
        float4 av = *(const float4*)(Aptr + k0);
        As[ak + 0][am] = av.x;
        As[ak + 1][am] = av.y;
        As[ak + 2][am] = av.z;
        As[ak + 3][am] = av.w;
#pragma unroll
        for (int kk = 0; kk < 4; kk++) {
            int k = bk0 + kk * 4;
            Bs[k][bc] = Bptr[(size_t)(k0 + k) * 64];
        }
        __syncthreads();
#pragma unroll
        for (int kk = 0; kk < BK; kk++) {
            float4 a = *(const float4*)&As[kk][tr];
            float4 b = *(const float4*)&Bs[kk][tc];
            acc[0][0] += a.x * b.x; acc[0][1] += a.x * b.y; acc[0][2] += a.x * b.z; acc[0][3] += a.x * b.w;
            acc[1][0] += a.y * b.x; acc[1][1] += a.y * b.y; acc[1][2] += a.y * b.z; acc[1][3] += a.y * b.w;
            acc[2][0] += a.z * b.x; acc[2][1] += a.z * b.y; acc[2][2] += a.z * b.z; acc[2][3] += a.z * b.w;
            acc[3][0] += a.w * b.x; acc[3][1] += a.w * b.y; acc[3][2] += a.w * b.z; acc[3][3] += a.w * b.w;
        }
        __syncthreads();
    }
#pragma unroll
    for (int i = 0; i < 4; i++) {
        float4 v = make_float4(acc[i][0], acc[i][1], acc[i][2], acc[i][3]);
        *(float4*)&C[(size_t)(row0 + tr + i) * ldc + col0 + tc] = v;
    }
}

// ---------------------------------------------------------------------------
// K3: f1 = Wh @ a[:64], f2 = Wh @ a[64:128] per (row, head). One wave each.
// ---------------------------------------------------------------------------
__global__ __launch_bounds__(64) void compute_f(const float* __restrict__ Wh,
                                                const float* __restrict__ a,
                                                float* __restrict__ f1,
                                                float* __restrict__ f2,
                                                int rowstride) {
    int i = blockIdx.x, h = blockIdx.y, lane = threadIdx.x;
    float v = Wh[(size_t)i * rowstride + h * 64 + lane];
    float p1 = v * a[h * 128 + lane];
    float p2 = v * a[h * 128 + 64 + lane];
#pragma unroll
    for (int off = 32; off; off >>= 1) {
        p1 += __shfl_down(p1, off);
        p2 += __shfl_down(p2, off);
    }
    if (lane == 0) {
        f1[(size_t)h * N_NODES + i] = p1;
        f2[(size_t)h * N_NODES + i] = p2;
    }
}

// ---------------------------------------------------------------------------
// K4: fused sparse attention: e = leakyrelu(f1_i + f2_j), softmax over
// neighbors, out_row = sum_j att_j * Wh[j, head*64: +64]  (+ optional ELU).
// One wave per (row, head).
// ---------------------------------------------------------------------------
template <bool ELU>
__global__ __launch_bounds__(64) void attn_agg(const float* __restrict__ Wh,
                                               const float* __restrict__ f1,
                                               const float* __restrict__ f2,
                                               const int* __restrict__ csr,
                                               const int* __restrict__ rowlen,
                                               float* __restrict__ out,
                                               int rowstride) {
    int i = blockIdx.x, h = blockIdx.y, lane = threadIdx.x;
    int len = rowlen[i];
    __shared__ float w[MAXDEG];
    __shared__ int cols[MAXDEG];
    const float* f2h = f2 + (size_t)h * N_NODES;
    float myf1 = f1[(size_t)h * N_NODES + i];

    float ev[4];
    int cv[4];
    float m = -1e30f;
#pragma unroll
    for (int c = 0; c < 4; c++) {
        int k = lane + c * 64;
        if (k < len) {
            int jj = csr[(size_t)i * MAXDEG + k];
            float e = myf1 + f2h[jj];
            e = e > 0.f ? e : ALPHA * e;
            ev[c] = e;
            cv[c] = jj;
            m = fmaxf(m, e);
        }
    }
#pragma unroll
    for (int off = 32; off; off >>= 1) m = fmaxf(m, __shfl_xor(m, off));
    float s = 0.f;
#pragma unroll
    for (int c = 0; c < 4; c++) {
        int k = lane + c * 64;
        if (k < len) {
            float ex = __expf(ev[c] - m);
            s += ex;
            w[k] = ex;
            cols[k] = cv[c];
        }
    }
#pragma unroll
    for (int off = 32; off; off >>= 1) s += __shfl_xor(s, off);
    __syncthreads();

    float acc = 0.f;
    for (int k = 0; k < len; k++) {
        acc += w[k] * Wh[(size_t)cols[k] * rowstride + h * 64 + lane];
    }
    float r = acc / s;
    if (ELU) r = r > 0.f ? r : __expf(r) - 1.0f;
    out[(size_t)i * rowstride + h * 64 + lane] = r;
}

// ---------------------------------------------------------------------------
// K5: tiny GEMM  out[4096][64] = h[4096][64] @ W[64][64]. One wave per row.
// ---------------------------------------------------------------------------
__global__ __launch_bounds__(64) void gemm64(const float* __restrict__ h,
                                             const float* __restrict__ W,
                                             float* __restrict__ out) {
    int i = blockIdx.x, lane = threadIdx.x;
    __shared__ float hrow[64];
    hrow[lane] = h[(size_t)i * 64 + lane];
    __syncthreads();
    float acc = 0.f;
#pragma unroll
    for (int k = 0; k < 64; k++) acc += hrow[k] * W[k * 64 + lane];
    out[(size_t)i * 64 + lane] = acc;
}

// ---------------------------------------------------------------------------
// K6: sparse normalized propagation: out_i = dinv_i * sum_j dinv_j * t_j  (+relu)
// ---------------------------------------------------------------------------
__global__ __launch_bounds__(64) void spmv_norm(const float* __restrict__ t,
                                                const float* __restrict__ dinv,
                                                const int* __restrict__ csr,
                                                const int* __restrict__ rowlen,
                                                float* __restrict__ out,
                                                int do_relu) {
    int i = blockIdx.x, lane = threadIdx.x;
    int len = rowlen[i];
    float acc = 0.f;
    for (int k = 0; k < len; k++) {
        int j = csr[(size_t)i * MAXDEG + k];
        acc += dinv[j] * t[(size_t)j * 64 + lane];
    }
    acc *= dinv[i];
    if (do_relu) acc = fmaxf(acc, 0.f);
    out[(size_t)i * 64 + lane] = acc;
}

// ---------------------------------------------------------------------------
// K7: out[4096][8] = h[4096][64] @ W_cls[64][8]
// ---------------------------------------------------------------------------
__global__ __launch_bounds__(64) void gemm_cls(const float* __restrict__ h,
                                               const float* __restrict__ W,
                                               float* __restrict__ out) {
    int i = blockIdx.x, lane = threadIdx.x;
    __shared__ float hrow[64];
    hrow[lane] = h[(size_t)i * 64 + lane];
    __syncthreads();
    int col = lane & 7;
    int k0 = (lane >> 3) * 8;
    float acc = 0.f;
#pragma unroll
    for (int k = 0; k < 8; k++) acc += hrow[k0 + k] * W[(k0 + k) * 8 + col];
    acc += __shfl_down(acc, 32);
    acc += __shfl_down(acc, 16);
    acc += __shfl_down(acc, 8);
    if (lane < 8) out[(size_t)i * 8 + lane] = acc;
}

// ---------------------------------------------------------------------------
// K8: final propagation into 8-wide output.
// lanes: col = lane&7, chunk = lane>>3 (8 chunks over neighbors)
// ---------------------------------------------------------------------------
__global__ __launch_bounds__(64) void spmv8(const float* __restrict__ t8,
                                            const float* __restrict__ dinv,
                                            const int* __restrict__ csr,
                                            const int* __restrict__ rowlen,
                                            float* __restrict__ out) {
    int i = blockIdx.x, lane = threadIdx.x;
    int len = rowlen[i];
    int col = lane & 7;
    int chunk = lane >> 3;
    float acc = 0.f;
    for (int k = chunk; k < len; k += 8) {
        int j = csr[(size_t)i * MAXDEG + k];
        acc += dinv[j] * t8[(size_t)j * 8 + col];
    }
    acc += __shfl_down(acc, 32);
    acc += __shfl_down(acc, 16);
    acc += __shfl_down(acc, 8);
    acc *= dinv[i];
    if (lane < 8) out[(size_t)i * 8 + lane] = acc;
}

// ---------------------------------------------------------------------------
extern "C" void kernel_launch(void* const* d_in, const int* in_sizes, int n_in,
                              void* d_out, int out_size, void* d_ws, size_t ws_size,
                              hipStream_t stream) {
    const float* x       = (const float*)d_in[0];   // [4096][1024]
    const int*   adj     = (const int*)d_in[1];     // [4096][4096]
    const float* W_heads = (const float*)d_in[2];   // [8][1024][64]
    const float* a_heads = (const float*)d_in[3];   // [8][128]
    const float* W_out   = (const float*)d_in[4];   // [512][64]
    const float* a_out   = (const float*)d_in[5];   // [128]
    const float* W_gcn   = (const float*)d_in[6];   // [3][64][64]
    const float* W_cls   = (const float*)d_in[7];   // [64][8]
    float* outp = (float*)d_out;                    // [4096][8]

    // workspace carve-up (~24.5 MB)
    float* ws      = (float*)d_ws;
    float* Wh_all  = ws;                                   // 4096*512
    float* hp      = Wh_all + (size_t)N_NODES * 512;       // 4096*512
    float* f1a     = hp + (size_t)N_NODES * 512;           // 8*4096
    float* f2a     = f1a + (size_t)NHEADS * N_NODES;       // 8*4096
    float* Wh2     = f2a + (size_t)NHEADS * N_NODES;       // 4096*64
    float* f1o     = Wh2 + (size_t)N_NODES * 64;           // 4096
    float* f2o     = f1o + N_NODES;                        // 4096
    float* h2      = f2o + N_NODES;                        // 4096*64
    float* t64     = h2 + (size_t)N_NODES * 64;            // 4096*64 (also t8)
    float* dinv    = t64 + (size_t)N_NODES * 64;           // 4096
    int*   rowlen  = (int*)(dinv + N_NODES);               // 4096
    int*   csr     = rowlen + N_NODES;                     // 4096*256

    // 1. CSR + dinv
    build_csr<<<N_NODES, 64, 0, stream>>>(adj, csr, rowlen, dinv);

    // 2. Wh_all = x @ W_heads   (M=4096, K=1024, N=512)
    gemm_tiled<<<dim3(N_NODES / BM, 512 / BN), 256, 0, stream>>>(x, W_heads, Wh_all, NFEAT, 512);

    // 3. f1/f2 per head
    compute_f<<<dim3(N_NODES, NHEADS), 64, 0, stream>>>(Wh_all, a_heads, f1a, f2a, 512);

    // 4. fused attention per head (+ELU) -> hp [4096][512]
    attn_agg<true><<<dim3(N_NODES, NHEADS), 64, 0, stream>>>(Wh_all, f1a, f2a, csr, rowlen, hp, 512);

    // 5. Wh2 = hp @ W_out  (M=4096, K=512, N=64)
    gemm_tiled<<<dim3(N_NODES / BM, 1), 256, 0, stream>>>(hp, W_out, Wh2, 512, 64);

    // 6. f1o/f2o
    compute_f<<<dim3(N_NODES, 1), 64, 0, stream>>>(Wh2, a_out, f1o, f2o, 64);

    // 7. out-layer attention (no ELU) -> h2 [4096][64]
    attn_agg<false><<<dim3(N_NODES, 1), 64, 0, stream>>>(Wh2, f1o, f2o, csr, rowlen, h2, 64);

    // 8. GCN blocks: h2 = relu(a_norm @ (h2 @ W_gcn[b]))
    for (int b = 0; b < NBLOCKS; b++) {
        gemm64<<<N_NODES, 64, 0, stream>>>(h2, W_gcn + (size_t)b * 64 * 64, t64);
        spmv_norm<<<N_NODES, 64, 0, stream>>>(t64, dinv, csr, rowlen, h2, 1);
    }

    // 9. head: out = a_norm @ (h2 @ W_cls)
    gemm_cls<<<N_NODES, 64, 0, stream>>>(h2, W_cls, t64);
    spmv8<<<N_NODES, 64, 0, stream>>>(t64, dinv, csr, rowlen, outp);
}

// Round 2
// 370.377 us; speedup vs baseline: 1.2140x; 1.2140x over previous
//
#include <hip/hip_runtime.h>
#include <hip/hip_bf16.h>
#include <math.h>

#define N_NODES 4096
#define NFEAT   1024
#define NHID    64
#define NHEADS  8
#define NCLASS  8
#define NBLOCKS 3
#define ALPHA   0.1f
#define MAXDEG  256

typedef short short8 __attribute__((ext_vector_type(8)));
typedef float f32x4  __attribute__((ext_vector_type(4)));

__device__ __forceinline__ ushort f2bf(float f) {
    uint b = __float_as_uint(f);
    b += 0x7FFFu + ((b >> 16) & 1u);            // round-to-nearest-even
    return (ushort)(b >> 16);
}
__device__ __forceinline__ float bf2f(ushort u) {
    return __uint_as_float(((uint)u) << 16);
}

// ---------------------------------------------------------------------------
// K1: build padded CSR + dinv = 1/sqrt(degree) from dense int adjacency.
// ---------------------------------------------------------------------------
__global__ __launch_bounds__(64) void build_csr(const int* __restrict__ adj,
                                                int* __restrict__ csr,
                                                int* __restrict__ rowlen,
                                                float* __restrict__ dinv) {
    int row = blockIdx.x;
    int lane = threadIdx.x;
    const int* arow = adj + (size_t)row * N_NODES;
    int count = 0;
    for (int base = 0; base < N_NODES; base += 64) {
        int v = arow[base + lane];
        unsigned long long m = __ballot(v != 0);
        int prefix = __popcll(m & ((1ull << lane) - 1ull));
        if (v != 0) {
            int pos = count + prefix;
            if (pos < MAXDEG) csr[(size_t)row * MAXDEG + pos] = base + lane;
        }
        count += __popcll(m);
    }
    if (lane == 0) {
        rowlen[row] = count < MAXDEG ? count : MAXDEG;
        dinv[row] = 1.0f / sqrtf((float)count);
    }
}

// ---------------------------------------------------------------------------
// K2a: split fp32 row-major matrix into bf16 hi + lo arrays (same layout).
// 4 elements per thread, exact-size grid.
// ---------------------------------------------------------------------------
__global__ __launch_bounds__(256) void split_x(const float* __restrict__ in,
                                               short* __restrict__ hi,
                                               short* __restrict__ lo) {
    size_t i = ((size_t)blockIdx.x * 256 + threadIdx.x) * 4;
    float4 v = *(const float4*)(in + i);
    ushort h0 = f2bf(v.x), h1 = f2bf(v.y), h2 = f2bf(v.z), h3 = f2bf(v.w);
    ushort l0 = f2bf(v.x - bf2f(h0));
    ushort l1 = f2bf(v.y - bf2f(h1));
    ushort l2 = f2bf(v.z - bf2f(h2));
    ushort l3 = f2bf(v.w - bf2f(h3));
    *(short4*)(hi + i) = make_short4((short)h0, (short)h1, (short)h2, (short)h3);
    *(short4*)(lo + i) = make_short4((short)l0, (short)l1, (short)l2, (short)l3);
}

// ---------------------------------------------------------------------------
// K2b: transpose+split weights.  in: [nheads][K][64] fp32 (head = n>>6),
// out: [N][K] bf16 hi/lo where row n = head (n>>6), col (n&63).
// grid: (N/64, K/64), 256 threads, LDS-transposed for coalesced writes.
// ---------------------------------------------------------------------------
__global__ __launch_bounds__(256) void tsplit(const float* __restrict__ W,
                                              short* __restrict__ out_hi,
                                              short* __restrict__ out_lo,
                                              int K) {
    __shared__ float tile[64][65];
    int n0 = blockIdx.x * 64, k0 = blockIdx.y * 64;
    int t = threadIdx.x;
    const float* src = W + (size_t)blockIdx.x * K * 64 + (size_t)k0 * 64;
#pragma unroll
    for (int i = 0; i < 16; i++) {
        int lin = t + i * 256;
        int kk = lin >> 6, nn = lin & 63;
        tile[nn][kk] = src[kk * 64 + nn];
    }
    __syncthreads();
#pragma unroll
    for (int i = 0; i < 16; i++) {
        int lin = t + i * 256;
        int nn = lin >> 6, kk = lin & 63;
        float v = tile[nn][kk];
        ushort h = f2bf(v);
        ushort l = f2bf(v - bf2f(h));
        size_t o = (size_t)(n0 + nn) * K + k0 + kk;
        out_hi[o] = (short)h;
        out_lo[o] = (short)l;
    }
}

// ---------------------------------------------------------------------------
// K3: MFMA GEMM with bf16x3 error-compensated split.
// C[M][ldc] = (Ah+Al)[M][K] @ (Bh+Bl)^T where B given as [N][K] row-major.
// Tile 128x64, BK=64, 4 waves (2x2), per-wave 64x32 (MR=4, NR=2).
// Double-buffered LDS + register prefetch, one barrier per K-tile.
// ---------------------------------------------------------------------------
#define GBM 128
#define GBN 64
#define GBK 64
#define LDK 72   // padded LDS stride in shorts (144 B)

__global__ __launch_bounds__(256) void gemm_mfma3(const short* __restrict__ Ah,
                                                  const short* __restrict__ Al,
                                                  const short* __restrict__ Bh,
                                                  const short* __restrict__ Bl,
                                                  float* __restrict__ C,
                                                  int K, int ldc) {
    __shared__ __align__(16) short As_h[2][GBM * LDK];
    __shared__ __align__(16) short As_l[2][GBM * LDK];
    __shared__ __align__(16) short Bs_h[2][GBN * LDK];
    __shared__ __align__(16) short Bs_l[2][GBN * LDK];

    int tid = threadIdx.x;
    int lane = tid & 63;
    int wid = tid >> 6;
    int wr = wid >> 1, wc = wid & 1;
    int row0 = blockIdx.x * GBM, col0 = blockIdx.y * GBN;

    int aRow[4], aKc[4], bRow[2], bKc[2];
#pragma unroll
    for (int c = 0; c < 4; c++) { int lin = tid + c * 256; aRow[c] = lin >> 3; aKc[c] = lin & 7; }
#pragma unroll
    for (int c = 0; c < 2; c++) { int lin = tid + c * 256; bRow[c] = lin >> 3; bKc[c] = lin & 7; }

    short8 rAh[4], rAl[4], rBh[2], rBl[2];

    auto LOAD = [&](int k0) {
#pragma unroll
        for (int c = 0; c < 4; c++) {
            size_t ga = (size_t)(row0 + aRow[c]) * K + k0 + aKc[c] * 8;
            rAh[c] = *(const short8*)(Ah + ga);
            rAl[c] = *(const short8*)(Al + ga);
        }
#pragma unroll
        for (int c = 0; c < 2; c++) {
            size_t gb = (size_t)(col0 + bRow[c]) * K + k0 + bKc[c] * 8;
            rBh[c] = *(const short8*)(Bh + gb);
            rBl[c] = *(const short8*)(Bl + gb);
        }
    };
    auto WRITE = [&](int buf) {
#pragma unroll
        for (int c = 0; c < 4; c++) {
            int o = aRow[c] * LDK + aKc[c] * 8;
            *(short8*)&As_h[buf][o] = rAh[c];
            *(short8*)&As_l[buf][o] = rAl[c];
        }
#pragma unroll
        for (int c = 0; c < 2; c++) {
            int o = bRow[c] * LDK + bKc[c] * 8;
            *(short8*)&Bs_h[buf][o] = rBh[c];
            *(short8*)&Bs_l[buf][o] = rBl[c];
        }
    };

    f32x4 acc[4][2];
#pragma unroll
    for (int m = 0; m < 4; m++)
#pragma unroll
        for (int n = 0; n < 2; n++) acc[m][n] = (f32x4){0.f, 0.f, 0.f, 0.f};

    LOAD(0);
    WRITE(0);
    __syncthreads();

    int nt = K / GBK;
    for (int t = 0; t < nt; ++t) {
        int cur = t & 1;
        if (t + 1 < nt) LOAD((t + 1) * GBK);
#pragma unroll
        for (int ks = 0; ks < 2; ++ks) {
            short8 ah[4], al[4], bh[2], bl[2];
            int ko = ks * 32 + (lane >> 4) * 8;
#pragma unroll
            for (int m = 0; m < 4; m++) {
                int r = (wr * 64 + m * 16 + (lane & 15)) * LDK + ko;
                ah[m] = *(const short8*)&As_h[cur][r];
                al[m] = *(const short8*)&As_l[cur][r];
            }
#pragma unroll
            for (int n = 0; n < 2; n++) {
                int r = (wc * 32 + n * 16 + (lane & 15)) * LDK + ko;
                bh[n] = *(const short8*)&Bs_h[cur][r];
                bl[n] = *(const short8*)&Bs_l[cur][r];
            }
#pragma unroll
            for (int m = 0; m < 4; m++)
#pragma unroll
                for (int n = 0; n < 2; n++) {
                    acc[m][n] = __builtin_amdgcn_mfma_f32_16x16x32_bf16(ah[m], bh[n], acc[m][n], 0, 0, 0);
                    acc[m][n] = __builtin_amdgcn_mfma_f32_16x16x32_bf16(ah[m], bl[n], acc[m][n], 0, 0, 0);
                    acc[m][n] = __builtin_amdgcn_mfma_f32_16x16x32_bf16(al[m], bh[n], acc[m][n], 0, 0, 0);
                }
        }
        if (t + 1 < nt) WRITE(cur ^ 1);
        __syncthreads();
    }

#pragma unroll
    for (int m = 0; m < 4; m++)
#pragma unroll
        for (int n = 0; n < 2; n++)
#pragma unroll
            for (int r = 0; r < 4; r++) {
                int rr = row0 + wr * 64 + m * 16 + (lane >> 4) * 4 + r;
                int cc = col0 + wc * 32 + n * 16 + (lane & 15);
                C[(size_t)rr * ldc + cc] = acc[m][n][r];
            }
}

// ---------------------------------------------------------------------------
// K4: f1 = Wh @ a[:64], f2 = Wh @ a[64:128] per (row, head).
// ---------------------------------------------------------------------------
__global__ __launch_bounds__(64) void compute_f(const float* __restrict__ Wh,
                                                const float* __restrict__ a,
                                                float* __restrict__ f1,
                                                float* __restrict__ f2,
                                                int rowstride) {
    int i = blockIdx.x, h = blockIdx.y, lane = threadIdx.x;
    float v = Wh[(size_t)i * rowstride + h * 64 + lane];
    float p1 = v * a[h * 128 + lane];
    float p2 = v * a[h * 128 + 64 + lane];
#pragma unroll
    for (int off = 32; off; off >>= 1) {
        p1 += __shfl_down(p1, off);
        p2 += __shfl_down(p2, off);
    }
    if (lane == 0) {
        f1[(size_t)h * N_NODES + i] = p1;
        f2[(size_t)h * N_NODES + i] = p2;
    }
}

// ---------------------------------------------------------------------------
// K5: fused sparse attention. One wave per (row, head).
// SPLIT: emit bf16 hi/lo (feeds MFMA gemm); else fp32.
// ---------------------------------------------------------------------------
template <bool ELU, bool SPLIT>
__global__ __launch_bounds__(64) void attn_agg(const float* __restrict__ Wh,
                                               const float* __restrict__ f1,
                                               const float* __restrict__ f2,
                                               const int* __restrict__ csr,
                                               const int* __restrict__ rowlen,
                                               float* __restrict__ outf,
                                               short* __restrict__ ohi,
                                               short* __restrict__ olo,
                                               int rowstride) {
    int i = blockIdx.x, h = blockIdx.y, lane = threadIdx.x;
    int len = rowlen[i];
    __shared__ float w[MAXDEG];
    __shared__ int cols[MAXDEG];
    const float* f2h = f2 + (size_t)h * N_NODES;
    float myf1 = f1[(size_t)h * N_NODES + i];

    float ev[4];
    int cv[4];
    float m = -1e30f;
#pragma unroll
    for (int c = 0; c < 4; c++) {
        int k = lane + c * 64;
        if (k < len) {
            int jj = csr[(size_t)i * MAXDEG + k];
            float e = myf1 + f2h[jj];
            e = e > 0.f ? e : ALPHA * e;
            ev[c] = e;
            cv[c] = jj;
            m = fmaxf(m, e);
        }
    }
#pragma unroll
    for (int off = 32; off; off >>= 1) m = fmaxf(m, __shfl_xor(m, off));
    float s = 0.f;
#pragma unroll
    for (int c = 0; c < 4; c++) {
        int k = lane + c * 64;
        if (k < len) {
            float ex = __expf(ev[c] - m);
            s += ex;
            w[k] = ex;
            cols[k] = cv[c];
        }
    }
#pragma unroll
    for (int off = 32; off; off >>= 1) s += __shfl_xor(s, off);
    __syncthreads();

    float acc = 0.f;
    for (int k = 0; k < len; k++) {
        acc += w[k] * Wh[(size_t)cols[k] * rowstride + h * 64 + lane];
    }
    float r = acc / s;
    if (ELU) r = r > 0.f ? r : __expf(r) - 1.0f;
    size_t o = (size_t)i * rowstride + h * 64 + lane;
    if (SPLIT) {
        ushort hh = f2bf(r);
        ohi[o] = (short)hh;
        olo[o] = (short)f2bf(r - bf2f(hh));
    } else {
        outf[o] = r;
    }
}

// ---------------------------------------------------------------------------
// K6: out[4096][64] = h[4096][64] @ W[64][64]. One wave per row.
// ---------------------------------------------------------------------------
__global__ __launch_bounds__(64) void gemm64(const float* __restrict__ h,
                                             const float* __restrict__ W,
                                             float* __restrict__ out) {
    int i = blockIdx.x, lane = threadIdx.x;
    __shared__ float hrow[64];
    hrow[lane] = h[(size_t)i * 64 + lane];
    __syncthreads();
    float acc = 0.f;
#pragma unroll
    for (int k = 0; k < 64; k++) acc += hrow[k] * W[k * 64 + lane];
    out[(size_t)i * 64 + lane] = acc;
}

// ---------------------------------------------------------------------------
// K7: sparse normalized propagation (+relu)
// ---------------------------------------------------------------------------
__global__ __launch_bounds__(64) void spmv_norm(const float* __restrict__ t,
                                                const float* __restrict__ dinv,
                                                const int* __restrict__ csr,
                                                const int* __restrict__ rowlen,
                                                float* __restrict__ out,
                                                int do_relu) {
    int i = blockIdx.x, lane = threadIdx.x;
    int len = rowlen[i];
    float acc = 0.f;
    for (int k = 0; k < len; k++) {
        int j = csr[(size_t)i * MAXDEG + k];
        acc += dinv[j] * t[(size_t)j * 64 + lane];
    }
    acc *= dinv[i];
    if (do_relu) acc = fmaxf(acc, 0.f);
    out[(size_t)i * 64 + lane] = acc;
}

// ---------------------------------------------------------------------------
// K8: out[4096][8] = h[4096][64] @ W_cls[64][8]
// ---------------------------------------------------------------------------
__global__ __launch_bounds__(64) void gemm_cls(const float* __restrict__ h,
                                               const float* __restrict__ W,
                                               float* __restrict__ out) {
    int i = blockIdx.x, lane = threadIdx.x;
    __shared__ float hrow[64];
    hrow[lane] = h[(size_t)i * 64 + lane];
    __syncthreads();
    int col = lane & 7;
    int k0 = (lane >> 3) * 8;
    float acc = 0.f;
#pragma unroll
    for (int k = 0; k < 8; k++) acc += hrow[k0 + k] * W[(k0 + k) * 8 + col];
    acc += __shfl_down(acc, 32);
    acc += __shfl_down(acc, 16);
    acc += __shfl_down(acc, 8);
    if (lane < 8) out[(size_t)i * 8 + lane] = acc;
}

// ---------------------------------------------------------------------------
// K9: final propagation into 8-wide output.
// ---------------------------------------------------------------------------
__global__ __launch_bounds__(64) void spmv8(const float* __restrict__ t8,
                                            const float* __restrict__ dinv,
                                            const int* __restrict__ csr,
                                            const int* __restrict__ rowlen,
                                            float* __restrict__ out) {
    int i = blockIdx.x, lane = threadIdx.x;
    int len = rowlen[i];
    int col = lane & 7;
    int chunk = lane >> 3;
    float acc = 0.f;
    for (int k = chunk; k < len; k += 8) {
        int j = csr[(size_t)i * MAXDEG + k];
        acc += dinv[j] * t8[(size_t)j * 8 + col];
    }
    acc += __shfl_down(acc, 32);
    acc += __shfl_down(acc, 16);
    acc += __shfl_down(acc, 8);
    acc *= dinv[i];
    if (lane < 8) out[(size_t)i * 8 + lane] = acc;
}

// ---------------------------------------------------------------------------
extern "C" void kernel_launch(void* const* d_in, const int* in_sizes, int n_in,
                              void* d_out, int out_size, void* d_ws, size_t ws_size,
                              hipStream_t stream) {
    const float* x       = (const float*)d_in[0];   // [4096][1024]
    const int*   adj     = (const int*)d_in[1];     // [4096][4096]
    const float* W_heads = (const float*)d_in[2];   // [8][1024][64]
    const float* a_heads = (const float*)d_in[3];   // [8][128]
    const float* W_out   = (const float*)d_in[4];   // [512][64]
    const float* a_out   = (const float*)d_in[5];   // [128]
    const float* W_gcn   = (const float*)d_in[6];   // [3][64][64]
    const float* W_cls   = (const float*)d_in[7];   // [64][8]
    float* outp = (float*)d_out;                    // [4096][8]

    // workspace carve-up (~33.5 MB)
    char* p = (char*)d_ws;
    short* x_hi   = (short*)p; p += (size_t)N_NODES * NFEAT * 2;       // 8 MB
    short* x_lo   = (short*)p; p += (size_t)N_NODES * NFEAT * 2;       // 8 MB
    short* Wt_hi  = (short*)p; p += (size_t)NHEADS * 64 * NFEAT * 2;   // 1 MB
    short* Wt_lo  = (short*)p; p += (size_t)NHEADS * 64 * NFEAT * 2;   // 1 MB
    short* Wt2_hi = (short*)p; p += (size_t)64 * 512 * 2;              // 64 KB
    short* Wt2_lo = (short*)p; p += (size_t)64 * 512 * 2;              // 64 KB
    float* Wh_all = (float*)p; p += (size_t)N_NODES * 512 * 4;         // 8 MB
    float* f1a    = (float*)p; p += (size_t)NHEADS * N_NODES * 4;
    float* f2a    = (float*)p; p += (size_t)NHEADS * N_NODES * 4;
    float* Wh2    = (float*)p; p += (size_t)N_NODES * 64 * 4;          // 1 MB
    float* f1o    = (float*)p; p += (size_t)N_NODES * 4;
    float* f2o    = (float*)p; p += (size_t)N_NODES * 4;
    float* h2     = (float*)p; p += (size_t)N_NODES * 64 * 4;          // 1 MB
    float* t64    = (float*)p; p += (size_t)N_NODES * 64 * 4;          // 1 MB
    float* dinv   = (float*)p; p += (size_t)N_NODES * 4;
    int*   rowlen = (int*)p;   p += (size_t)N_NODES * 4;
    int*   csr    = (int*)p;   p += (size_t)N_NODES * MAXDEG * 4;      // 4 MB

    // hp (attn layer-1 output, bf16 hi/lo) reuses the x split region: x is
    // dead after the first GEMM, and attn#1 reads Wh_all only.
    short* hp_hi = x_hi;
    short* hp_lo = x_lo;

    // 1. CSR + dinv
    build_csr<<<N_NODES, 64, 0, stream>>>(adj, csr, rowlen, dinv);

    // 2. precision-split inputs and weights (weights also transposed to [N][K])
    split_x<<<(N_NODES * NFEAT) / (256 * 4), 256, 0, stream>>>(x, x_hi, x_lo);
    tsplit<<<dim3(8, NFEAT / 64), 256, 0, stream>>>(W_heads, Wt_hi, Wt_lo, NFEAT);
    tsplit<<<dim3(1, 512 / 64), 256, 0, stream>>>(W_out, Wt2_hi, Wt2_lo, 512);

    // 3. Wh_all = x @ W_heads   (M=4096, K=1024, N=512) — MFMA bf16x3
    gemm_mfma3<<<dim3(N_NODES / GBM, 512 / GBN), 256, 0, stream>>>(
        x_hi, x_lo, Wt_hi, Wt_lo, Wh_all, NFEAT, 512);

    // 4. f1/f2 per head
    compute_f<<<dim3(N_NODES, NHEADS), 64, 0, stream>>>(Wh_all, a_heads, f1a, f2a, 512);

    // 5. fused attention per head (+ELU) -> hp bf16 hi/lo [4096][512]
    attn_agg<true, true><<<dim3(N_NODES, NHEADS), 64, 0, stream>>>(
        Wh_all, f1a, f2a, csr, rowlen, nullptr, hp_hi, hp_lo, 512);

    // 6. Wh2 = hp @ W_out  (M=4096, K=512, N=64) — MFMA bf16x3
    gemm_mfma3<<<dim3(N_NODES / GBM, 1), 256, 0, stream>>>(
        hp_hi, hp_lo, Wt2_hi, Wt2_lo, Wh2, 512, 64);

    // 7. f1o/f2o
    compute_f<<<dim3(N_NODES, 1), 64, 0, stream>>>(Wh2, a_out, f1o, f2o, 64);

    // 8. out-layer attention (no ELU) -> h2 fp32 [4096][64]
    attn_agg<false, false><<<dim3(N_NODES, 1), 64, 0, stream>>>(
        Wh2, f1o, f2o, csr, rowlen, h2, nullptr, nullptr, 64);

    // 9. GCN blocks: h2 = relu(a_norm @ (h2 @ W_gcn[b]))
    for (int b = 0; b < NBLOCKS; b++) {
        gemm64<<<N_NODES, 64, 0, stream>>>(h2, W_gcn + (size_t)b * 64 * 64, t64);
        spmv_norm<<<N_NODES, 64, 0, stream>>>(t64, dinv, csr, rowlen, h2, 1);
    }

    // 10. head: out = a_norm @ (h2 @ W_cls)
    gemm_cls<<<N_NODES, 64, 0, stream>>>(h2, W_cls, t64);
    spmv8<<<N_NODES, 64, 0, stream>>>(t64, dinv, csr, rowlen, outp);
}

// Round 3
// 290.739 us; speedup vs baseline: 1.5465x; 1.2739x over previous
//
#include <hip/hip_runtime.h>
#include <hip/hip_bf16.h>
#include <math.h>

#define N_NODES 4096
#define NFEAT   1024
#define NHEADS  8
#define NCLASS  8
#define ALPHA   0.1f
#define MAXDEG  256

typedef short short8 __attribute__((ext_vector_type(8)));
typedef float f32x4  __attribute__((ext_vector_type(4)));

__device__ __forceinline__ ushort f2bf(float f) {
    uint b = __float_as_uint(f);
    b += 0x7FFFu + ((b >> 16) & 1u);            // RNE
    return (ushort)(b >> 16);
}
__device__ __forceinline__ float bf2f(ushort u) {
    return __uint_as_float(((uint)u) << 16);
}

// ---------------------------------------------------------------------------
// K1: padded CSR + dinv from dense int adjacency, int4 loads (4x fewer iters).
// Ascending neighbor order preserved: lane L's 4 positions precede lane L+1's.
// ---------------------------------------------------------------------------
__global__ __launch_bounds__(64) void build_csr(const int* __restrict__ adj,
                                                int* __restrict__ csr,
                                                int* __restrict__ rowlen,
                                                float* __restrict__ dinv) {
    int row = blockIdx.x, lane = threadIdx.x;
    const int4* arow = (const int4*)(adj + (size_t)row * N_NODES);
    unsigned long long pre = (1ull << lane) - 1ull;
    int count = 0;
    int* crow = csr + (size_t)row * MAXDEG;
    for (int b = 0; b < N_NODES / 256; b++) {
        int4 v = arow[b * 64 + lane];
        unsigned long long m0 = __ballot(v.x != 0);
        unsigned long long m1 = __ballot(v.y != 0);
        unsigned long long m2 = __ballot(v.z != 0);
        unsigned long long m3 = __ballot(v.w != 0);
        int pos = count + __popcll(m0 & pre) + __popcll(m1 & pre)
                        + __popcll(m2 & pre) + __popcll(m3 & pre);
        int base = b * 256 + lane * 4;
        if (v.x) { if (pos < MAXDEG) crow[pos] = base;     pos++; }
        if (v.y) { if (pos < MAXDEG) crow[pos] = base + 1; pos++; }
        if (v.z) { if (pos < MAXDEG) crow[pos] = base + 2; pos++; }
        if (v.w) { if (pos < MAXDEG) crow[pos] = base + 3; pos++; }
        count += __popcll(m0) + __popcll(m1) + __popcll(m2) + __popcll(m3);
    }
    if (lane == 0) {
        rowlen[row] = count < MAXDEG ? count : MAXDEG;
        dinv[row] = 1.0f / sqrtf((float)count);
    }
}

// ---------------------------------------------------------------------------
// K2a: x -> x3 [4096][3072] bf16 concat-K segments [hi | lo | hi].
// ---------------------------------------------------------------------------
__global__ __launch_bounds__(256) void split_x(const float* __restrict__ in,
                                               short* __restrict__ x3) {
    size_t idx = ((size_t)blockIdx.x * 256 + threadIdx.x) * 4;
    int row = (int)(idx >> 10);
    int col = (int)(idx & 1023);
    float4 v = *(const float4*)(in + idx);
    ushort h0 = f2bf(v.x), h1 = f2bf(v.y), h2 = f2bf(v.z), h3 = f2bf(v.w);
    short4 h = make_short4((short)h0, (short)h1, (short)h2, (short)h3);
    short4 l = make_short4((short)f2bf(v.x - bf2f(h0)), (short)f2bf(v.y - bf2f(h1)),
                           (short)f2bf(v.z - bf2f(h2)), (short)f2bf(v.w - bf2f(h3)));
    short* rp = x3 + (size_t)row * 3072 + col;
    *(short4*)(rp)        = h;
    *(short4*)(rp + 1024) = l;
    *(short4*)(rp + 2048) = h;
}

// ---------------------------------------------------------------------------
// K2b: W [(nb)][K][64] fp32 -> B3 [nb*64][3K] bf16 segments [hi | hi | lo].
// grid (nb, K/64).
// ---------------------------------------------------------------------------
__global__ __launch_bounds__(256) void tsplit(const float* __restrict__ W,
                                              short* __restrict__ B3, int K) {
    __shared__ float tile[64][65];
    int k0 = blockIdx.y * 64, t = threadIdx.x;
    const float* src = W + (size_t)blockIdx.x * K * 64 + (size_t)k0 * 64;
#pragma unroll
    for (int i = 0; i < 16; i++) {
        int lin = t + i * 256;
        int kk = lin >> 6, nn = lin & 63;
        tile[nn][kk] = src[kk * 64 + nn];
    }
    __syncthreads();
#pragma unroll
    for (int i = 0; i < 16; i++) {
        int lin = t + i * 256;
        int nn = lin >> 6, kk = lin & 63;
        float v = tile[nn][kk];
        ushort h = f2bf(v);
        ushort l = f2bf(v - bf2f(h));
        short* rp = B3 + (size_t)(blockIdx.x * 64 + nn) * (3 * (size_t)K) + k0 + kk;
        rp[0]     = (short)h;
        rp[K]     = (short)h;
        rp[2 * K] = (short)l;
    }
}

// ---------------------------------------------------------------------------
// K3: standard bf16 MFMA GEMM over concat-K.  C = A'[M][Kp] @ B'[N][Kp]^T.
// Tile 128x64, BK=64, 4 waves (2x2), wave tile 64x32 (MR=4,NR=2).
// 55 KB LDS (2 blocks/CU), reg-staged double buffer, 1 barrier/tile.
// swz: XCD-grouping swizzle for the 256-block (32x8) gemm1 grid.
// split-K via blockIdx.z (kChunk columns each, partial C slabs).
// ---------------------------------------------------------------------------
#define GBM 128
#define GBN 64
#define GBK 64
#define LDK 72   // 144 B stride = 36 banks == 4 mod 32 -> 2-way (free)

__global__ __launch_bounds__(256) void gemm_mfma(const short* __restrict__ A,
                                                 const short* __restrict__ B,
                                                 float* __restrict__ C,
                                                 int Kp, int ldc, int kChunk,
                                                 int cPartStride, int swz) {
    __shared__ __align__(16) short As[2][GBM * LDK];
    __shared__ __align__(16) short Bs[2][GBN * LDK];

    int tid = threadIdx.x, lane = tid & 63, wid = tid >> 6;
    int wr = wid >> 1, wc = wid & 1;
    int bx, by;
    if (swz) {  // grid 256 linear: 4 A-panels x 8 B-panels per XCD
        int lin = blockIdx.x;
        bx = (lin & 7) * 4 + (lin >> 6);
        by = (lin >> 3) & 7;
    } else {
        bx = blockIdx.x; by = blockIdx.y;
    }
    int row0 = bx * GBM, col0 = by * GBN;
    int kbase = blockIdx.z * kChunk;
    C += (size_t)blockIdx.z * cPartStride;

    int aRow[4], aKc[4], bRow[2], bKc[2];
#pragma unroll
    for (int c = 0; c < 4; c++) { int lin = tid + c * 256; aRow[c] = lin >> 3; aKc[c] = (lin & 7) * 8; }
#pragma unroll
    for (int c = 0; c < 2; c++) { int lin = tid + c * 256; bRow[c] = lin >> 3; bKc[c] = (lin & 7) * 8; }

    short8 rA[4], rB[2];
    auto LOAD = [&](int k0) {
#pragma unroll
        for (int c = 0; c < 4; c++)
            rA[c] = *(const short8*)(A + (size_t)(row0 + aRow[c]) * Kp + kbase + k0 + aKc[c]);
#pragma unroll
        for (int c = 0; c < 2; c++)
            rB[c] = *(const short8*)(B + (size_t)(col0 + bRow[c]) * Kp + kbase + k0 + bKc[c]);
    };
    auto WRITE = [&](int buf) {
#pragma unroll
        for (int c = 0; c < 4; c++) *(short8*)&As[buf][aRow[c] * LDK + aKc[c]] = rA[c];
#pragma unroll
        for (int c = 0; c < 2; c++) *(short8*)&Bs[buf][bRow[c] * LDK + bKc[c]] = rB[c];
    };

    f32x4 acc[4][2];
#pragma unroll
    for (int m = 0; m < 4; m++)
#pragma unroll
        for (int n = 0; n < 2; n++) acc[m][n] = (f32x4){0.f, 0.f, 0.f, 0.f};

    LOAD(0);
    WRITE(0);
    __syncthreads();

    int nt = kChunk / GBK;
    for (int t = 0; t < nt; ++t) {
        int cur = t & 1;
        if (t + 1 < nt) LOAD((t + 1) * GBK);
#pragma unroll
        for (int ks = 0; ks < 2; ++ks) {
            short8 ah[4], bh[2];
            int ko = ks * 32 + (lane >> 4) * 8;
#pragma unroll
            for (int m = 0; m < 4; m++)
                ah[m] = *(const short8*)&As[cur][(wr * 64 + m * 16 + (lane & 15)) * LDK + ko];
#pragma unroll
            for (int n = 0; n < 2; n++)
                bh[n] = *(const short8*)&Bs[cur][(wc * 32 + n * 16 + (lane & 15)) * LDK + ko];
#pragma unroll
            for (int m = 0; m < 4; m++)
#pragma unroll
                for (int n = 0; n < 2; n++)
                    acc[m][n] = __builtin_amdgcn_mfma_f32_16x16x32_bf16(ah[m], bh[n], acc[m][n], 0, 0, 0);
        }
        if (t + 1 < nt) WRITE(cur ^ 1);
        __syncthreads();
    }

#pragma unroll
    for (int m = 0; m < 4; m++)
#pragma unroll
        for (int n = 0; n < 2; n++)
#pragma unroll
            for (int r = 0; r < 4; r++) {
                int rr = row0 + wr * 64 + m * 16 + (lane >> 4) * 4 + r;
                int cc = col0 + wc * 32 + n * 16 + (lane & 15);
                C[(size_t)rr * ldc + cc] = acc[m][n][r];
            }
}

// ---------------------------------------------------------------------------
// K4: per-row f1/f2 for all 8 heads -> transposed layouts f1t/f2t [N][8].
// 256 threads; 32-lane group per head.
// ---------------------------------------------------------------------------
__global__ __launch_bounds__(256) void compute_f1(const float* __restrict__ Wh,
                                                  const float* __restrict__ a,
                                                  float* __restrict__ f1t,
                                                  float* __restrict__ f2t) {
    int i = blockIdx.x, t = threadIdx.x, g = t >> 5, l = t & 31;
    const float* wr = Wh + (size_t)i * 512 + g * 64;
    float v0 = wr[l], v1 = wr[32 + l];
    const float* ag = a + g * 128;
    float p1 = v0 * ag[l] + v1 * ag[32 + l];
    float p2 = v0 * ag[64 + l] + v1 * ag[96 + l];
#pragma unroll
    for (int off = 16; off; off >>= 1) {
        p1 += __shfl_xor(p1, off, 32);
        p2 += __shfl_xor(p2, off, 32);
    }
    if (l == 0) {
        f1t[(size_t)i * 8 + g] = p1;
        f2t[(size_t)i * 8 + g] = p2;
    }
}

// ---------------------------------------------------------------------------
// K5: attn layer 1, all heads per row. 256 threads.
// Phase 1: stage cols + all-head f2 to LDS. Phase 2: per-head softmax in
// 32-lane groups. Phase 3: float2-per-thread gather over neighbors; emit
// hp3 bf16 concat-K [hi | lo | hi] with ELU.
// ---------------------------------------------------------------------------
__global__ __launch_bounds__(256) void attn1(const float* __restrict__ Wh,
                                             const float* __restrict__ f1t,
                                             const float* __restrict__ f2t,
                                             const int* __restrict__ csr,
                                             const int* __restrict__ rowlen,
                                             short* __restrict__ hp3) {
    __shared__ int cols[MAXDEG];
    __shared__ float ef[MAXDEG][9];     // +1 pad breaks 8-way bank pattern
    __shared__ float w8[8][MAXDEG];
    __shared__ float sinv[8];
    int i = blockIdx.x, t = threadIdx.x;
    int len = rowlen[i];

    if (t < len) {
        int j = csr[(size_t)i * MAXDEG + t];
        cols[t] = j;
        float4 fa = *(const float4*)(f2t + (size_t)j * 8);
        float4 fb = *(const float4*)(f2t + (size_t)j * 8 + 4);
        ef[t][0] = fa.x; ef[t][1] = fa.y; ef[t][2] = fa.z; ef[t][3] = fa.w;
        ef[t][4] = fb.x; ef[t][5] = fb.y; ef[t][6] = fb.z; ef[t][7] = fb.w;
    }
    __syncthreads();

    int g = t >> 5, l = t & 31;
    float f1v = f1t[(size_t)i * 8 + g];
    float m = -1e30f;
    for (int k = l; k < len; k += 32) {
        float e = f1v + ef[k][g];
        e = e > 0.f ? e : ALPHA * e;
        w8[g][k] = e;
        m = fmaxf(m, e);
    }
#pragma unroll
    for (int off = 16; off; off >>= 1) m = fmaxf(m, __shfl_xor(m, off, 32));
    float s = 0.f;
    for (int k = l; k < len; k += 32) {
        float ex = __expf(w8[g][k] - m);
        w8[g][k] = ex;
        s += ex;
    }
#pragma unroll
    for (int off = 16; off; off >>= 1) s += __shfl_xor(s, off, 32);
    if (l == 0) sinv[g] = 1.0f / s;
    __syncthreads();

    int c = t * 2;
    int hh = c >> 6;
    const float* base = Wh + c;
    const float* wrow = w8[hh];
    float a0 = 0.f, a1 = 0.f;
#pragma unroll 4
    for (int k = 0; k < len; k++) {
        int j = cols[k];
        float wv = wrow[k];
        float2 v = *(const float2*)(base + (size_t)j * 512);
        a0 += wv * v.x;
        a1 += wv * v.y;
    }
    float iv = sinv[hh];
    a0 *= iv; a1 *= iv;
    a0 = a0 > 0.f ? a0 : __expf(a0) - 1.f;       // ELU
    a1 = a1 > 0.f ? a1 : __expf(a1) - 1.f;
    ushort h0 = f2bf(a0), h1 = f2bf(a1);
    ushort l0 = f2bf(a0 - bf2f(h0)), l1 = f2bf(a1 - bf2f(h1));
    short* rp = hp3 + (size_t)i * 1536 + c;
    *(short2*)(rp)        = make_short2((short)h0, (short)h1);
    *(short2*)(rp + 512)  = make_short2((short)l0, (short)l1);
    *(short2*)(rp + 1024) = make_short2((short)h0, (short)h1);
}

// ---------------------------------------------------------------------------
// K6: sum split-K partials -> Wh2, and compute f1o/f2o (layer-2 scalars).
// ---------------------------------------------------------------------------
__global__ __launch_bounds__(64) void f2sum(const float* __restrict__ part,
                                            const float* __restrict__ a,
                                            float* __restrict__ Wh2,
                                            float* __restrict__ f1o,
                                            float* __restrict__ f2o) {
    int i = blockIdx.x, l = threadIdx.x;
    size_t o = (size_t)i * 64 + l;
    const size_t S = (size_t)N_NODES * 64;
    float v = part[o] + part[o + S] + part[o + 2 * S] + part[o + 3 * S];
    Wh2[o] = v;
    float p1 = v * a[l], p2 = v * a[64 + l];
#pragma unroll
    for (int off = 32; off; off >>= 1) {
        p1 += __shfl_xor(p1, off);
        p2 += __shfl_xor(p2, off);
    }
    if (l == 0) { f1o[i] = p1; f2o[i] = p2; }
}

// ---------------------------------------------------------------------------
// K7: attn layer 2 (no ELU) fused with first GCN matmul: t0 = h2row @ W0.
// One wave per row.
// ---------------------------------------------------------------------------
__global__ __launch_bounds__(64) void attn2_g0(const float* __restrict__ Wh2,
                                               const float* __restrict__ f1o,
                                               const float* __restrict__ f2o,
                                               const int* __restrict__ csr,
                                               const int* __restrict__ rowlen,
                                               const float* __restrict__ W0,
                                               float* __restrict__ t0) {
    int i = blockIdx.x, lane = threadIdx.x;
    int len = rowlen[i];
    __shared__ float w[MAXDEG];
    __shared__ int cl[MAXDEG];
    __shared__ float hrow[64];
    float myf1 = f1o[i];

    float ev[4]; int cv[4];
    float m = -1e30f;
#pragma unroll
    for (int c = 0; c < 4; c++) {
        int k = lane + c * 64;
        if (k < len) {
            int j = csr[(size_t)i * MAXDEG + k];
            float e = myf1 + f2o[j];
            e = e > 0.f ? e : ALPHA * e;
            ev[c] = e; cv[c] = j;
            m = fmaxf(m, e);
        }
    }
#pragma unroll
    for (int off = 32; off; off >>= 1) m = fmaxf(m, __shfl_xor(m, off));
    float s = 0.f;
#pragma unroll
    for (int c = 0; c < 4; c++) {
        int k = lane + c * 64;
        if (k < len) {
            float ex = __expf(ev[c] - m);
            s += ex;
            w[k] = ex;
            cl[k] = cv[c];
        }
    }
#pragma unroll
    for (int off = 32; off; off >>= 1) s += __shfl_xor(s, off);
    float iv = 1.0f / s;
    __syncthreads();

    float acc = 0.f;
#pragma unroll 4
    for (int k = 0; k < len; k++)
        acc += w[k] * Wh2[(size_t)cl[k] * 64 + lane];
    hrow[lane] = acc * iv;
    __syncthreads();
    float o = 0.f;
#pragma unroll
    for (int k = 0; k < 64; k++) o += hrow[k] * W0[k * 64 + lane];
    t0[(size_t)i * 64 + lane] = o;
}

// ---------------------------------------------------------------------------
// K8: fused GCN step: h = relu(dinv_i * sum_j dinv_j * t_j); out = h @ W.
// ---------------------------------------------------------------------------
__global__ __launch_bounds__(64) void spmv_gemm(const float* __restrict__ t,
                                                const float* __restrict__ dinv,
                                                const int* __restrict__ csr,
                                                const int* __restrict__ rowlen,
                                                const float* __restrict__ W,
                                                float* __restrict__ out) {
    int i = blockIdx.x, lane = threadIdx.x;
    int len = rowlen[i];
    const int* ci = csr + (size_t)i * MAXDEG;
    float acc = 0.f;
#pragma unroll 4
    for (int k = 0; k < len; k++) {
        int j = ci[k];
        acc += dinv[j] * t[(size_t)j * 64 + lane];
    }
    __shared__ float hrow[64];
    hrow[lane] = fmaxf(acc * dinv[i], 0.f);
    __syncthreads();
    float o = 0.f;
#pragma unroll
    for (int k = 0; k < 64; k++) o += hrow[k] * W[k * 64 + lane];
    out[(size_t)i * 64 + lane] = o;
}

// ---------------------------------------------------------------------------
// K9: fused final GCN step into classifier: h = relu(spmv); t8 = h @ Wcls.
// ---------------------------------------------------------------------------
__global__ __launch_bounds__(64) void spmv_cls(const float* __restrict__ t,
                                               const float* __restrict__ dinv,
                                               const int* __restrict__ csr,
                                               const int* __restrict__ rowlen,
                                               const float* __restrict__ Wc,
                                               float* __restrict__ t8) {
    int i = blockIdx.x, lane = threadIdx.x;
    int len = rowlen[i];
    const int* ci = csr + (size_t)i * MAXDEG;
    float acc = 0.f;
#pragma unroll 4
    for (int k = 0; k < len; k++) {
        int j = ci[k];
        acc += dinv[j] * t[(size_t)j * 64 + lane];
    }
    __shared__ float hrow[64];
    hrow[lane] = fmaxf(acc * dinv[i], 0.f);
    __syncthreads();
    int col = lane & 7, k0 = (lane >> 3) * 8;
    float o = 0.f;
#pragma unroll
    for (int k = 0; k < 8; k++) o += hrow[k0 + k] * Wc[(k0 + k) * 8 + col];
    o += __shfl_down(o, 32);
    o += __shfl_down(o, 16);
    o += __shfl_down(o, 8);
    if (lane < 8) t8[(size_t)i * 8 + lane] = o;
}

// ---------------------------------------------------------------------------
// K10: final propagation: out = a_norm @ t8.
// ---------------------------------------------------------------------------
__global__ __launch_bounds__(64) void spmv8(const float* __restrict__ t8,
                                            const float* __restrict__ dinv,
                                            const int* __restrict__ csr,
                                            const int* __restrict__ rowlen,
                                            float* __restrict__ out) {
    int i = blockIdx.x, lane = threadIdx.x;
    int len = rowlen[i];
    int col = lane & 7, chunk = lane >> 3;
    float acc = 0.f;
    for (int k = chunk; k < len; k += 8) {
        int j = csr[(size_t)i * MAXDEG + k];
        acc += dinv[j] * t8[(size_t)j * 8 + col];
    }
    acc += __shfl_down(acc, 32);
    acc += __shfl_down(acc, 16);
    acc += __shfl_down(acc, 8);
    acc *= dinv[i];
    if (lane < 8) out[(size_t)i * 8 + lane] = acc;
}

// ---------------------------------------------------------------------------
extern "C" void kernel_launch(void* const* d_in, const int* in_sizes, int n_in,
                              void* d_out, int out_size, void* d_ws, size_t ws_size,
                              hipStream_t stream) {
    const float* x       = (const float*)d_in[0];   // [4096][1024]
    const int*   adj     = (const int*)d_in[1];     // [4096][4096]
    const float* W_heads = (const float*)d_in[2];   // [8][1024][64]
    const float* a_heads = (const float*)d_in[3];   // [8][128]
    const float* W_out   = (const float*)d_in[4];   // [512][64]
    const float* a_out   = (const float*)d_in[5];   // [128]
    const float* W_gcn   = (const float*)d_in[6];   // [3][64][64]
    const float* W_cls   = (const float*)d_in[7];   // [64][8]
    float* outp = (float*)d_out;                    // [4096][8]

    // workspace carve-up (~45 MB)
    char* p = (char*)d_ws;
    short* x3     = (short*)p; p += (size_t)N_NODES * 3072 * 2;   // 25.2 MB
    short* W3     = (short*)p; p += (size_t)512 * 3072 * 2;       // 3.1 MB
    short* W23    = (short*)p; p += (size_t)64 * 1536 * 2;        // 192 KB
    float* Wh_all = (float*)p; p += (size_t)N_NODES * 512 * 4;    // 8 MB
    float* f1t    = (float*)p; p += (size_t)N_NODES * 8 * 4;
    float* f2t    = (float*)p; p += (size_t)N_NODES * 8 * 4;
    float* Wh2    = (float*)p; p += (size_t)N_NODES * 64 * 4;     // 1 MB
    float* f1o    = (float*)p; p += (size_t)N_NODES * 4;
    float* f2o    = (float*)p; p += (size_t)N_NODES * 4;
    float* tA     = (float*)p; p += (size_t)N_NODES * 64 * 4;     // 1 MB
    float* tB     = (float*)p; p += (size_t)N_NODES * 64 * 4;     // 1 MB
    float* t8     = (float*)p; p += (size_t)N_NODES * 8 * 4;
    float* dinv   = (float*)p; p += (size_t)N_NODES * 4;
    int*   rowlen = (int*)p;   p += (size_t)N_NODES * 4;
    int*   csr    = (int*)p;   p += (size_t)N_NODES * MAXDEG * 4; // 4 MB

    // Aliases inside the x3 region (x3 dead after gemm1):
    // hp3 = bytes [0, 12.6MB); part = bytes [16MB, 20MB).
    short* hp3  = x3;
    float* part = (float*)((char*)x3 + (16u << 20));

    // 1. CSR + dinv
    build_csr<<<N_NODES, 64, 0, stream>>>(adj, csr, rowlen, dinv);

    // 2. splits (concat-K layouts)
    split_x<<<(N_NODES * NFEAT) / (256 * 4), 256, 0, stream>>>(x, x3);
    tsplit<<<dim3(NHEADS, NFEAT / 64), 256, 0, stream>>>(W_heads, W3, NFEAT);
    tsplit<<<dim3(1, 512 / 64), 256, 0, stream>>>(W_out, W23, 512);

    // 3. Wh_all = x' @ W'  (M=4096, N=512, K'=3072), XCD-swizzled 256 blocks
    gemm_mfma<<<256, 256, 0, stream>>>(x3, W3, Wh_all, 3072, 512, 3072, 0, 1);

    // 4. f1/f2 (all heads per row)
    compute_f1<<<N_NODES, 256, 0, stream>>>(Wh_all, a_heads, f1t, f2t);

    // 5. attn layer 1 (+ELU) -> hp3 bf16 concat-K [4096][1536]
    attn1<<<N_NODES, 256, 0, stream>>>(Wh_all, f1t, f2t, csr, rowlen, hp3);

    // 6. Wh2 partials = hp' @ W2'  (K'=1536, split-K=4 -> 128 blocks)
    gemm_mfma<<<dim3(N_NODES / GBM, 1, 4), 256, 0, stream>>>(
        hp3, W23, part, 1536, 64, 384, N_NODES * 64, 0);

    // 7. sum partials + f1o/f2o
    f2sum<<<N_NODES, 64, 0, stream>>>(part, a_out, Wh2, f1o, f2o);

    // 8. attn layer 2 + (@ W_gcn[0]) -> tA
    attn2_g0<<<N_NODES, 64, 0, stream>>>(Wh2, f1o, f2o, csr, rowlen, W_gcn, tA);

    // 9. GCN blocks 1,2 fused (spmv+relu+matmul)
    spmv_gemm<<<N_NODES, 64, 0, stream>>>(tA, dinv, csr, rowlen, W_gcn + 4096, tB);
    spmv_gemm<<<N_NODES, 64, 0, stream>>>(tB, dinv, csr, rowlen, W_gcn + 8192, tA);

    // 10. final block + classifier, then last propagation
    spmv_cls<<<N_NODES, 64, 0, stream>>>(tA, dinv, csr, rowlen, W_cls, t8);
    spmv8<<<N_NODES, 64, 0, stream>>>(t8, dinv, csr, rowlen, outp);
}

// Round 4
// 267.234 us; speedup vs baseline: 1.6826x; 1.0880x over previous
//
#include <hip/hip_runtime.h>
#include <hip/hip_bf16.h>
#include <math.h>

#define N_NODES 4096
#define NFEAT   1024
#define NHEADS  8
#define ALPHA   0.1f
#define MAXDEG  256

typedef short short8 __attribute__((ext_vector_type(8)));
typedef float f32x4  __attribute__((ext_vector_type(4)));

__device__ __forceinline__ ushort f2bf(float f) {
    uint b = __float_as_uint(f);
    b += 0x7FFFu + ((b >> 16) & 1u);            // RNE
    return (ushort)(b >> 16);
}
__device__ __forceinline__ float bf2f(ushort u) {
    return __uint_as_float(((uint)u) << 16);
}

// ---------------------------------------------------------------------------
// K1: padded CSR (ushort indices) + dinv, int4 loads.
// ---------------------------------------------------------------------------
__global__ __launch_bounds__(64) void build_csr(const int* __restrict__ adj,
                                                ushort* __restrict__ csr,
                                                int* __restrict__ rowlen,
                                                float* __restrict__ dinv) {
    int row = blockIdx.x, lane = threadIdx.x;
    const int4* arow = (const int4*)(adj + (size_t)row * N_NODES);
    unsigned long long pre = (1ull << lane) - 1ull;
    int count = 0;
    ushort* crow = csr + (size_t)row * MAXDEG;
    for (int b = 0; b < N_NODES / 256; b++) {
        int4 v = arow[b * 64 + lane];
        unsigned long long m0 = __ballot(v.x != 0);
        unsigned long long m1 = __ballot(v.y != 0);
        unsigned long long m2 = __ballot(v.z != 0);
        unsigned long long m3 = __ballot(v.w != 0);
        int pos = count + __popcll(m0 & pre) + __popcll(m1 & pre)
                        + __popcll(m2 & pre) + __popcll(m3 & pre);
        int base = b * 256 + lane * 4;
        if (v.x) { if (pos < MAXDEG) crow[pos] = (ushort)base;       pos++; }
        if (v.y) { if (pos < MAXDEG) crow[pos] = (ushort)(base + 1); pos++; }
        if (v.z) { if (pos < MAXDEG) crow[pos] = (ushort)(base + 2); pos++; }
        if (v.w) { if (pos < MAXDEG) crow[pos] = (ushort)(base + 3); pos++; }
        count += __popcll(m0) + __popcll(m1) + __popcll(m2) + __popcll(m3);
    }
    if (lane == 0) {
        rowlen[row] = count < MAXDEG ? count : MAXDEG;
        dinv[row] = 1.0f / sqrtf((float)count);
    }
}

// ---------------------------------------------------------------------------
// K2: merged prep. Blocks [0,4096): x -> x3 [4096][3072] bf16 [hi|lo|hi].
// Blocks [4096,4224): W_heads -> W3 [512][3072] bf16 [hi|hi|lo].
// Blocks [4224,4232): W_out  -> W23 [64][1536].
// ---------------------------------------------------------------------------
__global__ __launch_bounds__(256) void prep(const float* __restrict__ x,
                                            const float* __restrict__ Whd,
                                            const float* __restrict__ Wo,
                                            short* __restrict__ x3,
                                            short* __restrict__ W3,
                                            short* __restrict__ W23) {
    __shared__ float tile[64][65];
    int b = blockIdx.x, t = threadIdx.x;
    if (b < 4096) {
        size_t idx = ((size_t)b * 256 + t) * 4;
        int row = (int)(idx >> 10);
        int col = (int)(idx & 1023);
        float4 v = *(const float4*)(x + idx);
        ushort h0 = f2bf(v.x), h1 = f2bf(v.y), h2 = f2bf(v.z), h3 = f2bf(v.w);
        short4 h = make_short4((short)h0, (short)h1, (short)h2, (short)h3);
        short4 l = make_short4((short)f2bf(v.x - bf2f(h0)), (short)f2bf(v.y - bf2f(h1)),
                               (short)f2bf(v.z - bf2f(h2)), (short)f2bf(v.w - bf2f(h3)));
        short* rp = x3 + (size_t)row * 3072 + col;
        *(short4*)(rp)        = h;
        *(short4*)(rp + 1024) = l;
        *(short4*)(rp + 2048) = h;
        return;
    }
    const float* W; short* B3; int K, head, kb;
    if (b < 4096 + 128) { int id = b - 4096; W = Whd; B3 = W3;  K = 1024; head = id >> 4; kb = id & 15; }
    else                { int id = b - 4224; W = Wo;  B3 = W23; K = 512;  head = 0;       kb = id; }
    int k0 = kb * 64;
    const float* src = W + (size_t)head * K * 64 + (size_t)k0 * 64;
#pragma unroll
    for (int i = 0; i < 16; i++) {
        int lin = t + i * 256;
        int kk = lin >> 6, nn = lin & 63;
        tile[nn][kk] = src[kk * 64 + nn];
    }
    __syncthreads();
#pragma unroll
    for (int i = 0; i < 16; i++) {
        int lin = t + i * 256;
        int nn = lin >> 6, kk = lin & 63;
        float v = tile[nn][kk];
        ushort h = f2bf(v);
        ushort l = f2bf(v - bf2f(h));
        short* rp = B3 + (size_t)(head * 64 + nn) * (3 * (size_t)K) + k0 + kk;
        rp[0]     = (short)h;
        rp[K]     = (short)h;
        rp[2 * K] = (short)l;
    }
}

// ---------------------------------------------------------------------------
// K3: bf16 MFMA GEMM over concat-K.  C = A'[M][Kp] @ B'[N][Kp]^T.
// Tile 128x64, BK=64, 4 waves, reg-staged double buffer.
// headmajor: C-write to Whh[head][row][64] (head = col>>6).
// ---------------------------------------------------------------------------
#define GBM 128
#define GBN 64
#define GBK 64
#define LDK 72

__global__ __launch_bounds__(256) void gemm_mfma(const short* __restrict__ A,
                                                 const short* __restrict__ B,
                                                 float* __restrict__ C,
                                                 int Kp, int ldc, int kChunk,
                                                 int cPartStride, int swz, int headmajor) {
    __shared__ __align__(16) short As[2][GBM * LDK];
    __shared__ __align__(16) short Bs[2][GBN * LDK];

    int tid = threadIdx.x, lane = tid & 63, wid = tid >> 6;
    int wr = wid >> 1, wc = wid & 1;
    int bx, by;
    if (swz) {
        int lin = blockIdx.x;
        bx = (lin & 7) * 4 + (lin >> 6);
        by = (lin >> 3) & 7;
    } else {
        bx = blockIdx.x; by = blockIdx.y;
    }
    int row0 = bx * GBM, col0 = by * GBN;
    int kbase = blockIdx.z * kChunk;
    C += (size_t)blockIdx.z * cPartStride;

    int aRow[4], aKc[4], bRow[2], bKc[2];
#pragma unroll
    for (int c = 0; c < 4; c++) { int lin = tid + c * 256; aRow[c] = lin >> 3; aKc[c] = (lin & 7) * 8; }
#pragma unroll
    for (int c = 0; c < 2; c++) { int lin = tid + c * 256; bRow[c] = lin >> 3; bKc[c] = (lin & 7) * 8; }

    short8 rA[4], rB[2];
    auto LOAD = [&](int k0) {
#pragma unroll
        for (int c = 0; c < 4; c++)
            rA[c] = *(const short8*)(A + (size_t)(row0 + aRow[c]) * Kp + kbase + k0 + aKc[c]);
#pragma unroll
        for (int c = 0; c < 2; c++)
            rB[c] = *(const short8*)(B + (size_t)(col0 + bRow[c]) * Kp + kbase + k0 + bKc[c]);
    };
    auto WRITE = [&](int buf) {
#pragma unroll
        for (int c = 0; c < 4; c++) *(short8*)&As[buf][aRow[c] * LDK + aKc[c]] = rA[c];
#pragma unroll
        for (int c = 0; c < 2; c++) *(short8*)&Bs[buf][bRow[c] * LDK + bKc[c]] = rB[c];
    };

    f32x4 acc[4][2];
#pragma unroll
    for (int m = 0; m < 4; m++)
#pragma unroll
        for (int n = 0; n < 2; n++) acc[m][n] = (f32x4){0.f, 0.f, 0.f, 0.f};

    LOAD(0);
    WRITE(0);
    __syncthreads();

    int nt = kChunk / GBK;
    for (int t = 0; t < nt; ++t) {
        int cur = t & 1;
        if (t + 1 < nt) LOAD((t + 1) * GBK);
#pragma unroll
        for (int ks = 0; ks < 2; ++ks) {
            short8 ah[4], bh[2];
            int ko = ks * 32 + (lane >> 4) * 8;
#pragma unroll
            for (int m = 0; m < 4; m++)
                ah[m] = *(const short8*)&As[cur][(wr * 64 + m * 16 + (lane & 15)) * LDK + ko];
#pragma unroll
            for (int n = 0; n < 2; n++)
                bh[n] = *(const short8*)&Bs[cur][(wc * 32 + n * 16 + (lane & 15)) * LDK + ko];
#pragma unroll
            for (int m = 0; m < 4; m++)
#pragma unroll
                for (int n = 0; n < 2; n++)
                    acc[m][n] = __builtin_amdgcn_mfma_f32_16x16x32_bf16(ah[m], bh[n], acc[m][n], 0, 0, 0);
        }
        if (t + 1 < nt) WRITE(cur ^ 1);
        __syncthreads();
    }

#pragma unroll
    for (int m = 0; m < 4; m++)
#pragma unroll
        for (int n = 0; n < 2; n++)
#pragma unroll
            for (int r = 0; r < 4; r++) {
                int rr = row0 + wr * 64 + m * 16 + (lane >> 4) * 4 + r;
                int cc = col0 + wc * 32 + n * 16 + (lane & 15);
                if (headmajor)
                    C[(size_t)(cc >> 6) * N_NODES * 64 + (size_t)rr * 64 + (cc & 63)] = acc[m][n][r];
                else
                    C[(size_t)rr * ldc + cc] = acc[m][n][r];
            }
}

// ---------------------------------------------------------------------------
// K4: f1/f2 per (row, head) from head-major Whh -> f1h/f2h [8][4096].
// ---------------------------------------------------------------------------
__global__ __launch_bounds__(256) void compute_f1(const float* __restrict__ Whh,
                                                  const float* __restrict__ a,
                                                  float* __restrict__ f1h,
                                                  float* __restrict__ f2h) {
    int i = blockIdx.x, t = threadIdx.x, g = t >> 5, l = t & 31;
    const float* wr = Whh + ((size_t)g * N_NODES + i) * 64;
    float v0 = wr[l], v1 = wr[32 + l];
    const float* ag = a + g * 128;
    float p1 = v0 * ag[l] + v1 * ag[32 + l];
    float p2 = v0 * ag[64 + l] + v1 * ag[96 + l];
#pragma unroll
    for (int off = 16; off; off >>= 1) {
        p1 += __shfl_xor(p1, off, 32);
        p2 += __shfl_xor(p2, off, 32);
    }
    if (l == 0) {
        f1h[(size_t)g * N_NODES + i] = p1;
        f2h[(size_t)g * N_NODES + i] = p2;
    }
}

// ---------------------------------------------------------------------------
// K5: attn layer 1. One wave per (row, head); 4 rows bundled per block,
// head = blockIdx&7 so round-robin block->XCD pins each head's 1MB Whh
// slice (+2MB csr16) into one XCD's L2. ILP-4 gather. No cross-wave LDS
// sharing -> no barriers.
// ---------------------------------------------------------------------------
__global__ __launch_bounds__(256) void attn1(const float* __restrict__ Whh,
                                             const float* __restrict__ f1h,
                                             const float* __restrict__ f2h,
                                             const ushort* __restrict__ csr,
                                             const int* __restrict__ rowlen,
                                             short* __restrict__ hp3) {
    __shared__ float  w[4][MAXDEG];
    __shared__ ushort cols[4][MAXDEG];
    int lin = blockIdx.x;
    int h = lin & 7;
    int rq = lin >> 3;
    int wid = threadIdx.x >> 6, lane = threadIdx.x & 63;
    int i = rq * 4 + wid;
    int len = rowlen[i];
    const ushort* crow = csr + (size_t)i * MAXDEG;
    const float* f2p = f2h + (size_t)h * N_NODES;
    float f1v = f1h[(size_t)h * N_NODES + i];

    float ev[4]; int cv[4];
    float m = -1e30f;
#pragma unroll
    for (int c = 0; c < 4; c++) {
        int k = lane + c * 64;
        if (k < len) {
            int j = crow[k];
            float e = f1v + f2p[j];
            e = e > 0.f ? e : ALPHA * e;
            ev[c] = e; cv[c] = j;
            m = fmaxf(m, e);
        }
    }
#pragma unroll
    for (int off = 32; off; off >>= 1) m = fmaxf(m, __shfl_xor(m, off));
    float s = 0.f;
#pragma unroll
    for (int c = 0; c < 4; c++) {
        int k = lane + c * 64;
        if (k < len) {
            float ex = __expf(ev[c] - m);
            s += ex;
            w[wid][k] = ex;
            cols[wid][k] = (ushort)cv[c];
        }
    }
#pragma unroll
    for (int off = 32; off; off >>= 1) s += __shfl_xor(s, off);
    float sinv = 1.0f / s;

    const float* base = Whh + (size_t)h * N_NODES * 64 + lane;
    float a0 = 0.f, a1 = 0.f, a2 = 0.f, a3 = 0.f;
    int k = 0;
    for (; k + 4 <= len; k += 4) {
        int j0 = cols[wid][k], j1 = cols[wid][k + 1], j2 = cols[wid][k + 2], j3 = cols[wid][k + 3];
        float w0 = w[wid][k], w1 = w[wid][k + 1], w2 = w[wid][k + 2], w3 = w[wid][k + 3];
        a0 += w0 * base[(size_t)j0 * 64];
        a1 += w1 * base[(size_t)j1 * 64];
        a2 += w2 * base[(size_t)j2 * 64];
        a3 += w3 * base[(size_t)j3 * 64];
    }
    for (; k < len; k++) a0 += w[wid][k] * base[(size_t)cols[wid][k] * 64];
    float acc = ((a0 + a1) + (a2 + a3)) * sinv;
    acc = acc > 0.f ? acc : __expf(acc) - 1.f;     // ELU
    ushort hh = f2bf(acc);
    ushort ll = f2bf(acc - bf2f(hh));
    short* rp = hp3 + (size_t)i * 1536 + h * 64 + lane;
    rp[0]    = (short)hh;
    rp[512]  = (short)ll;
    rp[1024] = (short)hh;
}

// ---------------------------------------------------------------------------
// K6: sum gemm2 split-K partials -> Wh2, compute f1o/f2o.
// ---------------------------------------------------------------------------
__global__ __launch_bounds__(64) void f2sum(const float* __restrict__ part,
                                            const float* __restrict__ a,
                                            float* __restrict__ Wh2,
                                            float* __restrict__ f1o,
                                            float* __restrict__ f2o) {
    int i = blockIdx.x, l = threadIdx.x;
    size_t o = (size_t)i * 64 + l;
    const size_t S = (size_t)N_NODES * 64;
    float v = part[o] + part[o + S] + part[o + 2 * S] + part[o + 3 * S];
    Wh2[o] = v;
    float p1 = v * a[l], p2 = v * a[64 + l];
#pragma unroll
    for (int off = 32; off; off >>= 1) {
        p1 += __shfl_xor(p1, off);
        p2 += __shfl_xor(p2, off);
    }
    if (l == 0) { f1o[i] = p1; f2o[i] = p2; }
}

// ---------------------------------------------------------------------------
// K7: attn layer 2 (no ELU) + first GCN matmul; output pre-scaled by dinv_i.
// 4 rows/block, one wave each.
// ---------------------------------------------------------------------------
__global__ __launch_bounds__(256) void attn2_g0(const float* __restrict__ Wh2,
                                                const float* __restrict__ f1o,
                                                const float* __restrict__ f2o,
                                                const ushort* __restrict__ csr,
                                                const int* __restrict__ rowlen,
                                                const float* __restrict__ W0,
                                                const float* __restrict__ dinv,
                                                float* __restrict__ t0) {
    __shared__ float  w[4][MAXDEG];
    __shared__ ushort cl[4][MAXDEG];
    __shared__ float  hrow[4][64];
    int wid = threadIdx.x >> 6, lane = threadIdx.x & 63;
    int i = blockIdx.x * 4 + wid;
    int len = rowlen[i];
    const ushort* crow = csr + (size_t)i * MAXDEG;
    float myf1 = f1o[i];

    float ev[4]; int cv[4];
    float m = -1e30f;
#pragma unroll
    for (int c = 0; c < 4; c++) {
        int k = lane + c * 64;
        if (k < len) {
            int j = crow[k];
            float e = myf1 + f2o[j];
            e = e > 0.f ? e : ALPHA * e;
            ev[c] = e; cv[c] = j;
            m = fmaxf(m, e);
        }
    }
#pragma unroll
    for (int off = 32; off; off >>= 1) m = fmaxf(m, __shfl_xor(m, off));
    float s = 0.f;
#pragma unroll
    for (int c = 0; c < 4; c++) {
        int k = lane + c * 64;
        if (k < len) {
            float ex = __expf(ev[c] - m);
            s += ex;
            w[wid][k] = ex;
            cl[wid][k] = (ushort)cv[c];
        }
    }
#pragma unroll
    for (int off = 32; off; off >>= 1) s += __shfl_xor(s, off);
    float sinv = 1.0f / s;

    float a0 = 0.f, a1 = 0.f, a2 = 0.f, a3 = 0.f;
    int k = 0;
    for (; k + 4 <= len; k += 4) {
        int j0 = cl[wid][k], j1 = cl[wid][k + 1], j2 = cl[wid][k + 2], j3 = cl[wid][k + 3];
        a0 += w[wid][k]     * Wh2[(size_t)j0 * 64 + lane];
        a1 += w[wid][k + 1] * Wh2[(size_t)j1 * 64 + lane];
        a2 += w[wid][k + 2] * Wh2[(size_t)j2 * 64 + lane];
        a3 += w[wid][k + 3] * Wh2[(size_t)j3 * 64 + lane];
    }
    for (; k < len; k++) a0 += w[wid][k] * Wh2[(size_t)cl[wid][k] * 64 + lane];
    hrow[wid][lane] = ((a0 + a1) + (a2 + a3)) * sinv;

    float o = 0.f;
#pragma unroll
    for (int kk = 0; kk < 64; kk++) o += hrow[wid][kk] * W0[kk * 64 + lane];
    t0[(size_t)i * 64 + lane] = o * dinv[i];
}

// ---------------------------------------------------------------------------
// K8: GCN step on pre-scaled input: h = relu(dinv_i * sum t'_j);
// out = dinv_i * (h @ W).  4 rows/block.
// ---------------------------------------------------------------------------
__global__ __launch_bounds__(256) void spmv_gemm(const float* __restrict__ t,
                                                 const ushort* __restrict__ csr,
                                                 const int* __restrict__ rowlen,
                                                 const float* __restrict__ W,
                                                 const float* __restrict__ dinv,
                                                 float* __restrict__ out) {
    __shared__ float hrow[4][64];
    int wid = threadIdx.x >> 6, lane = threadIdx.x & 63;
    int i = blockIdx.x * 4 + wid;
    int len = rowlen[i];
    const ushort* ci = csr + (size_t)i * MAXDEG;
    float a0 = 0.f, a1 = 0.f, a2 = 0.f, a3 = 0.f;
    int k = 0;
    for (; k + 4 <= len; k += 4) {
        a0 += t[(size_t)ci[k]     * 64 + lane];
        a1 += t[(size_t)ci[k + 1] * 64 + lane];
        a2 += t[(size_t)ci[k + 2] * 64 + lane];
        a3 += t[(size_t)ci[k + 3] * 64 + lane];
    }
    for (; k < len; k++) a0 += t[(size_t)ci[k] * 64 + lane];
    float di = dinv[i];
    hrow[wid][lane] = fmaxf(((a0 + a1) + (a2 + a3)) * di, 0.f);
    float o = 0.f;
#pragma unroll
    for (int kk = 0; kk < 64; kk++) o += hrow[wid][kk] * W[kk * 64 + lane];
    out[(size_t)i * 64 + lane] = o * di;
}

// ---------------------------------------------------------------------------
// K9: final GCN step into classifier: h = relu(dinv_i * sum t'_j);
// t8' = dinv_i * (h @ Wcls).  4 rows/block.
// ---------------------------------------------------------------------------
__global__ __launch_bounds__(256) void spmv_cls(const float* __restrict__ t,
                                                const ushort* __restrict__ csr,
                                                const int* __restrict__ rowlen,
                                                const float* __restrict__ Wc,
                                                const float* __restrict__ dinv,
                                                float* __restrict__ t8) {
    __shared__ float hrow[4][64];
    int wid = threadIdx.x >> 6, lane = threadIdx.x & 63;
    int i = blockIdx.x * 4 + wid;
    int len = rowlen[i];
    const ushort* ci = csr + (size_t)i * MAXDEG;
    float a0 = 0.f, a1 = 0.f, a2 = 0.f, a3 = 0.f;
    int k = 0;
    for (; k + 4 <= len; k += 4) {
        a0 += t[(size_t)ci[k]     * 64 + lane];
        a1 += t[(size_t)ci[k + 1] * 64 + lane];
        a2 += t[(size_t)ci[k + 2] * 64 + lane];
        a3 += t[(size_t)ci[k + 3] * 64 + lane];
    }
    for (; k < len; k++) a0 += t[(size_t)ci[k] * 64 + lane];
    float di = dinv[i];
    hrow[wid][lane] = fmaxf(((a0 + a1) + (a2 + a3)) * di, 0.f);
    int col = lane & 7, k0 = (lane >> 3) * 8;
    float o = 0.f;
#pragma unroll
    for (int kk = 0; kk < 8; kk++) o += hrow[wid][k0 + kk] * Wc[(k0 + kk) * 8 + col];
    o += __shfl_down(o, 32);
    o += __shfl_down(o, 16);
    o += __shfl_down(o, 8);
    if (lane < 8) t8[(size_t)i * 8 + lane] = o * di;
}

// ---------------------------------------------------------------------------
// K10: final propagation on pre-scaled t8': out_i = dinv_i * sum t8'_j.
// ---------------------------------------------------------------------------
__global__ __launch_bounds__(256) void spmv8(const float* __restrict__ t8,
                                             const ushort* __restrict__ csr,
                                             const int* __restrict__ rowlen,
                                             const float* __restrict__ dinv,
                                             float* __restrict__ out) {
    int wid = threadIdx.x >> 6, lane = threadIdx.x & 63;
    int i = blockIdx.x * 4 + wid;
    int len = rowlen[i];
    const ushort* ci = csr + (size_t)i * MAXDEG;
    int col = lane & 7, chunk = lane >> 3;
    float acc = 0.f;
    for (int k = chunk; k < len; k += 8)
        acc += t8[(size_t)ci[k] * 8 + col];
    acc += __shfl_down(acc, 32);
    acc += __shfl_down(acc, 16);
    acc += __shfl_down(acc, 8);
    if (lane < 8) out[(size_t)i * 8 + lane] = acc * dinv[i];
}

// ---------------------------------------------------------------------------
extern "C" void kernel_launch(void* const* d_in, const int* in_sizes, int n_in,
                              void* d_out, int out_size, void* d_ws, size_t ws_size,
                              hipStream_t stream) {
    const float* x       = (const float*)d_in[0];
    const int*   adj     = (const int*)d_in[1];
    const float* W_heads = (const float*)d_in[2];
    const float* a_heads = (const float*)d_in[3];
    const float* W_out   = (const float*)d_in[4];
    const float* a_out   = (const float*)d_in[5];
    const float* W_gcn   = (const float*)d_in[6];
    const float* W_cls   = (const float*)d_in[7];
    float* outp = (float*)d_out;

    // workspace carve-up (~42.6 MB)
    char* p = (char*)d_ws;
    short*  x3     = (short*)p;  p += (size_t)N_NODES * 3072 * 2;     // 25.2 MB
    short*  W3     = (short*)p;  p += (size_t)512 * 3072 * 2;         // 3.1 MB
    short*  W23    = (short*)p;  p += (size_t)64 * 1536 * 2;
    float*  Whh    = (float*)p;  p += (size_t)NHEADS * N_NODES * 64 * 4;  // 8 MB head-major
    float*  f1h    = (float*)p;  p += (size_t)NHEADS * N_NODES * 4;
    float*  f2h    = (float*)p;  p += (size_t)NHEADS * N_NODES * 4;
    float*  Wh2    = (float*)p;  p += (size_t)N_NODES * 64 * 4;
    float*  f1o    = (float*)p;  p += (size_t)N_NODES * 4;
    float*  f2o    = (float*)p;  p += (size_t)N_NODES * 4;
    float*  tA     = (float*)p;  p += (size_t)N_NODES * 64 * 4;
    float*  tB     = (float*)p;  p += (size_t)N_NODES * 64 * 4;
    float*  t8     = (float*)p;  p += (size_t)N_NODES * 8 * 4;
    float*  dinv   = (float*)p;  p += (size_t)N_NODES * 4;
    int*    rowlen = (int*)p;    p += (size_t)N_NODES * 4;
    ushort* csr    = (ushort*)p; p += (size_t)N_NODES * MAXDEG * 2;   // 2 MB

    // aliases inside x3 (dead after gemm1): hp3 [0,12.6MB), part [16,20MB)
    short* hp3  = x3;
    float* part = (float*)((char*)x3 + (16u << 20));

    build_csr<<<N_NODES, 64, 0, stream>>>(adj, csr, rowlen, dinv);

    prep<<<4096 + 128 + 8, 256, 0, stream>>>(x, W_heads, W_out, x3, W3, W23);

    // gemm1: Whh (head-major) = x' @ W'  (M=4096, N=512, K'=3072)
    gemm_mfma<<<256, 256, 0, stream>>>(x3, W3, Whh, 3072, 512, 3072, 0, 1, 1);

    compute_f1<<<N_NODES, 256, 0, stream>>>(Whh, a_heads, f1h, f2h);

    // attn layer 1 (+ELU) -> hp3 concat-K [4096][1536]; head-per-XCD grid
    attn1<<<N_NODES * NHEADS / 4, 256, 0, stream>>>(Whh, f1h, f2h, csr, rowlen, hp3);

    // gemm2: Wh2 partials = hp' @ W2' (K'=1536, split-K=4)
    gemm_mfma<<<dim3(N_NODES / GBM, 1, 4), 256, 0, stream>>>(
        hp3, W23, part, 1536, 64, 384, N_NODES * 64, 0, 0);

    f2sum<<<N_NODES, 64, 0, stream>>>(part, a_out, Wh2, f1o, f2o);

    attn2_g0<<<N_NODES / 4, 256, 0, stream>>>(Wh2, f1o, f2o, csr, rowlen, W_gcn, dinv, tA);

    spmv_gemm<<<N_NODES / 4, 256, 0, stream>>>(tA, csr, rowlen, W_gcn + 4096, dinv, tB);
    spmv_gemm<<<N_NODES / 4, 256, 0, stream>>>(tB, csr, rowlen, W_gcn + 8192, dinv, tA);

    spmv_cls<<<N_NODES / 4, 256, 0, stream>>>(tA, csr, rowlen, W_cls, dinv, t8);
    spmv8<<<N_NODES / 4, 256, 0, stream>>>(t8, csr, rowlen, dinv, outp);
}

// Round 5
// 257.652 us; speedup vs baseline: 1.7451x; 1.0372x over previous
//
#include <hip/hip_runtime.h>
#include <hip/hip_bf16.h>
#include <math.h>

#define N_NODES 4096
#define NFEAT   1024
#define NHEADS  8
#define ALPHA   0.1f
#define MAXDEG  256

typedef short short8 __attribute__((ext_vector_type(8)));
typedef float f32x4  __attribute__((ext_vector_type(4)));

__device__ __forceinline__ ushort f2bf(float f) {
    uint b = __float_as_uint(f);
    b += 0x7FFFu + ((b >> 16) & 1u);            // RNE
    return (ushort)(b >> 16);
}
__device__ __forceinline__ float bf2f(ushort u) {
    return __uint_as_float(((uint)u) << 16);
}

// ---------------------------------------------------------------------------
// K1: padded CSR (ushort indices) + dinv, int4 loads.
// ---------------------------------------------------------------------------
__global__ __launch_bounds__(64) void build_csr(const int* __restrict__ adj,
                                                ushort* __restrict__ csr,
                                                int* __restrict__ rowlen,
                                                float* __restrict__ dinv) {
    int row = blockIdx.x, lane = threadIdx.x;
    const int4* arow = (const int4*)(adj + (size_t)row * N_NODES);
    unsigned long long pre = (1ull << lane) - 1ull;
    int count = 0;
    ushort* crow = csr + (size_t)row * MAXDEG;
    for (int b = 0; b < N_NODES / 256; b++) {
        int4 v = arow[b * 64 + lane];
        unsigned long long m0 = __ballot(v.x != 0);
        unsigned long long m1 = __ballot(v.y != 0);
        unsigned long long m2 = __ballot(v.z != 0);
        unsigned long long m3 = __ballot(v.w != 0);
        int pos = count + __popcll(m0 & pre) + __popcll(m1 & pre)
                        + __popcll(m2 & pre) + __popcll(m3 & pre);
        int base = b * 256 + lane * 4;
        if (v.x) { if (pos < MAXDEG) crow[pos] = (ushort)base;       pos++; }
        if (v.y) { if (pos < MAXDEG) crow[pos] = (ushort)(base + 1); pos++; }
        if (v.z) { if (pos < MAXDEG) crow[pos] = (ushort)(base + 2); pos++; }
        if (v.w) { if (pos < MAXDEG) crow[pos] = (ushort)(base + 3); pos++; }
        count += __popcll(m0) + __popcll(m1) + __popcll(m2) + __popcll(m3);
    }
    if (lane == 0) {
        rowlen[row] = count < MAXDEG ? count : MAXDEG;
        dinv[row] = 1.0f / sqrtf((float)count);
    }
}

// ---------------------------------------------------------------------------
// K2: merged prep (x split + weight transpose/split, concat-K layouts).
// ---------------------------------------------------------------------------
__global__ __launch_bounds__(256) void prep(const float* __restrict__ x,
                                            const float* __restrict__ Whd,
                                            const float* __restrict__ Wo,
                                            short* __restrict__ x3,
                                            short* __restrict__ W3,
                                            short* __restrict__ W23) {
    __shared__ float tile[64][65];
    int b = blockIdx.x, t = threadIdx.x;
    if (b < 4096) {
        size_t idx = ((size_t)b * 256 + t) * 4;
        int row = (int)(idx >> 10);
        int col = (int)(idx & 1023);
        float4 v = *(const float4*)(x + idx);
        ushort h0 = f2bf(v.x), h1 = f2bf(v.y), h2 = f2bf(v.z), h3 = f2bf(v.w);
        short4 h = make_short4((short)h0, (short)h1, (short)h2, (short)h3);
        short4 l = make_short4((short)f2bf(v.x - bf2f(h0)), (short)f2bf(v.y - bf2f(h1)),
                               (short)f2bf(v.z - bf2f(h2)), (short)f2bf(v.w - bf2f(h3)));
        short* rp = x3 + (size_t)row * 3072 + col;
        *(short4*)(rp)        = h;
        *(short4*)(rp + 1024) = l;
        *(short4*)(rp + 2048) = h;
        return;
    }
    const float* W; short* B3; int K, head, kb;
    if (b < 4096 + 128) { int id = b - 4096; W = Whd; B3 = W3;  K = 1024; head = id >> 4; kb = id & 15; }
    else                { int id = b - 4224; W = Wo;  B3 = W23; K = 512;  head = 0;       kb = id; }
    int k0 = kb * 64;
    const float* src = W + (size_t)head * K * 64 + (size_t)k0 * 64;
#pragma unroll
    for (int i = 0; i < 16; i++) {
        int lin = t + i * 256;
        int kk = lin >> 6, nn = lin & 63;
        tile[nn][kk] = src[kk * 64 + nn];
    }
    __syncthreads();
#pragma unroll
    for (int i = 0; i < 16; i++) {
        int lin = t + i * 256;
        int nn = lin >> 6, kk = lin & 63;
        float v = tile[nn][kk];
        ushort h = f2bf(v);
        ushort l = f2bf(v - bf2f(h));
        short* rp = B3 + (size_t)(head * 64 + nn) * (3 * (size_t)K) + k0 + kk;
        rp[0]     = (short)h;
        rp[K]     = (short)h;
        rp[2 * K] = (short)l;
    }
}

// ---------------------------------------------------------------------------
// K3: bf16 MFMA GEMM over concat-K (unchanged from round 4).
// ---------------------------------------------------------------------------
#define GBM 128
#define GBN 64
#define GBK 64
#define LDK 72

__global__ __launch_bounds__(256) void gemm_mfma(const short* __restrict__ A,
                                                 const short* __restrict__ B,
                                                 float* __restrict__ C,
                                                 int Kp, int ldc, int kChunk,
                                                 int cPartStride, int swz, int headmajor) {
    __shared__ __align__(16) short As[2][GBM * LDK];
    __shared__ __align__(16) short Bs[2][GBN * LDK];

    int tid = threadIdx.x, lane = tid & 63, wid = tid >> 6;
    int wr = wid >> 1, wc = wid & 1;
    int bx, by;
    if (swz) {
        int lin = blockIdx.x;
        bx = (lin & 7) * 4 + (lin >> 6);
        by = (lin >> 3) & 7;
    } else {
        bx = blockIdx.x; by = blockIdx.y;
    }
    int row0 = bx * GBM, col0 = by * GBN;
    int kbase = blockIdx.z * kChunk;
    C += (size_t)blockIdx.z * cPartStride;

    int aRow[4], aKc[4], bRow[2], bKc[2];
#pragma unroll
    for (int c = 0; c < 4; c++) { int lin = tid + c * 256; aRow[c] = lin >> 3; aKc[c] = (lin & 7) * 8; }
#pragma unroll
    for (int c = 0; c < 2; c++) { int lin = tid + c * 256; bRow[c] = lin >> 3; bKc[c] = (lin & 7) * 8; }

    short8 rA[4], rB[2];
    auto LOAD = [&](int k0) {
#pragma unroll
        for (int c = 0; c < 4; c++)
            rA[c] = *(const short8*)(A + (size_t)(row0 + aRow[c]) * Kp + kbase + k0 + aKc[c]);
#pragma unroll
        for (int c = 0; c < 2; c++)
            rB[c] = *(const short8*)(B + (size_t)(col0 + bRow[c]) * Kp + kbase + k0 + bKc[c]);
    };
    auto WRITE = [&](int buf) {
#pragma unroll
        for (int c = 0; c < 4; c++) *(short8*)&As[buf][aRow[c] * LDK + aKc[c]] = rA[c];
#pragma unroll
        for (int c = 0; c < 2; c++) *(short8*)&Bs[buf][bRow[c] * LDK + bKc[c]] = rB[c];
    };

    f32x4 acc[4][2];
#pragma unroll
    for (int m = 0; m < 4; m++)
#pragma unroll
        for (int n = 0; n < 2; n++) acc[m][n] = (f32x4){0.f, 0.f, 0.f, 0.f};

    LOAD(0);
    WRITE(0);
    __syncthreads();

    int nt = kChunk / GBK;
    for (int t = 0; t < nt; ++t) {
        int cur = t & 1;
        if (t + 1 < nt) LOAD((t + 1) * GBK);
#pragma unroll
        for (int ks = 0; ks < 2; ++ks) {
            short8 ah[4], bh[2];
            int ko = ks * 32 + (lane >> 4) * 8;
#pragma unroll
            for (int m = 0; m < 4; m++)
                ah[m] = *(const short8*)&As[cur][(wr * 64 + m * 16 + (lane & 15)) * LDK + ko];
#pragma unroll
            for (int n = 0; n < 2; n++)
                bh[n] = *(const short8*)&Bs[cur][(wc * 32 + n * 16 + (lane & 15)) * LDK + ko];
#pragma unroll
            for (int m = 0; m < 4; m++)
#pragma unroll
                for (int n = 0; n < 2; n++)
                    acc[m][n] = __builtin_amdgcn_mfma_f32_16x16x32_bf16(ah[m], bh[n], acc[m][n], 0, 0, 0);
        }
        if (t + 1 < nt) WRITE(cur ^ 1);
        __syncthreads();
    }

#pragma unroll
    for (int m = 0; m < 4; m++)
#pragma unroll
        for (int n = 0; n < 2; n++)
#pragma unroll
            for (int r = 0; r < 4; r++) {
                int rr = row0 + wr * 64 + m * 16 + (lane >> 4) * 4 + r;
                int cc = col0 + wc * 32 + n * 16 + (lane & 15);
                if (headmajor)
                    C[(size_t)(cc >> 6) * N_NODES * 64 + (size_t)rr * 64 + (cc & 63)] = acc[m][n][r];
                else
                    C[(size_t)rr * ldc + cc] = acc[m][n][r];
            }
}

// ---------------------------------------------------------------------------
// K4: f1/f2 per (row, head) from head-major Whh.
// ---------------------------------------------------------------------------
__global__ __launch_bounds__(256) void compute_f1(const float* __restrict__ Whh,
                                                  const float* __restrict__ a,
                                                  float* __restrict__ f1h,
                                                  float* __restrict__ f2h) {
    int i = blockIdx.x, t = threadIdx.x, g = t >> 5, l = t & 31;
    const float* wr = Whh + ((size_t)g * N_NODES + i) * 64;
    float v0 = wr[l], v1 = wr[32 + l];
    const float* ag = a + g * 128;
    float p1 = v0 * ag[l] + v1 * ag[32 + l];
    float p2 = v0 * ag[64 + l] + v1 * ag[96 + l];
#pragma unroll
    for (int off = 16; off; off >>= 1) {
        p1 += __shfl_xor(p1, off, 32);
        p2 += __shfl_xor(p2, off, 32);
    }
    if (l == 0) {
        f1h[(size_t)g * N_NODES + i] = p1;
        f2h[(size_t)g * N_NODES + i] = p2;
    }
}

// ---------------------------------------------------------------------------
// K5: attn layer 1. Wave per (row, head); head = blockIdx&7 (XCD pinning).
// Gather: q = lane>>4 neighbor slot, d = lane&15 dim quarter, float4 loads,
// unroll x2, cross-q shfl reduction. Lanes<16 do ELU + bf16 split + store.
// ---------------------------------------------------------------------------
__global__ __launch_bounds__(256) void attn1(const float* __restrict__ Whh,
                                             const float* __restrict__ f1h,
                                             const float* __restrict__ f2h,
                                             const ushort* __restrict__ csr,
                                             const int* __restrict__ rowlen,
                                             short* __restrict__ hp3) {
    __shared__ float  w[4][MAXDEG];
    __shared__ ushort cols[4][MAXDEG];
    int lin = blockIdx.x;
    int h = lin & 7;
    int rq = lin >> 3;
    int wid = threadIdx.x >> 6, lane = threadIdx.x & 63;
    int i = rq * 4 + wid;
    int len = rowlen[i];
    const ushort* crow = csr + (size_t)i * MAXDEG;
    const float* f2p = f2h + (size_t)h * N_NODES;
    float f1v = f1h[(size_t)h * N_NODES + i];

    float ev[4]; int cv[4];
    float m = -1e30f;
#pragma unroll
    for (int c = 0; c < 4; c++) {
        int k = lane + c * 64;
        if (k < len) {
            int j = crow[k];
            float e = f1v + f2p[j];
            e = e > 0.f ? e : ALPHA * e;
            ev[c] = e; cv[c] = j;
            m = fmaxf(m, e);
        }
    }
#pragma unroll
    for (int off = 32; off; off >>= 1) m = fmaxf(m, __shfl_xor(m, off));
    float s = 0.f;
#pragma unroll
    for (int c = 0; c < 4; c++) {
        int k = lane + c * 64;
        if (k < len) {
            float ex = __expf(ev[c] - m);
            s += ex;
            w[wid][k] = ex;
            cols[wid][k] = (ushort)cv[c];
        }
    }
#pragma unroll
    for (int off = 32; off; off >>= 1) s += __shfl_xor(s, off);
    float sinv = 1.0f / s;

    int len8 = (len + 7) & ~7;
    if (lane < len8 - len) {            // zero-pad so gather needs no guards
        w[wid][len + lane] = 0.f;
        cols[wid][len + lane] = 0;
    }

    int q = lane >> 4, d = lane & 15;
    const float4* base = (const float4*)(Whh + (size_t)h * (N_NODES * 64)) + d;
    float ax0 = 0.f, ay0 = 0.f, az0 = 0.f, aw0 = 0.f;
    float ax1 = 0.f, ay1 = 0.f, az1 = 0.f, aw1 = 0.f;
    for (int k = 0; k < len8; k += 8) {
        int   j0 = cols[wid][k + q];
        int   j1 = cols[wid][k + 4 + q];
        float w0 = w[wid][k + q];
        float w1 = w[wid][k + 4 + q];
        float4 v0 = base[(size_t)j0 * 16];
        float4 v1 = base[(size_t)j1 * 16];
        ax0 += w0 * v0.x; ay0 += w0 * v0.y; az0 += w0 * v0.z; aw0 += w0 * v0.w;
        ax1 += w1 * v1.x; ay1 += w1 * v1.y; az1 += w1 * v1.z; aw1 += w1 * v1.w;
    }
    float rx = ax0 + ax1, ry = ay0 + ay1, rz = az0 + az1, rw = aw0 + aw1;
#pragma unroll
    for (int off = 16; off <= 32; off <<= 1) {
        rx += __shfl_xor(rx, off);
        ry += __shfl_xor(ry, off);
        rz += __shfl_xor(rz, off);
        rw += __shfl_xor(rw, off);
    }
    if (lane < 16) {
        float v[4] = {rx * sinv, ry * sinv, rz * sinv, rw * sinv};
        short hi[4], lo[4];
#pragma unroll
        for (int c = 0; c < 4; c++) {
            float e = v[c] > 0.f ? v[c] : __expf(v[c]) - 1.f;   // ELU
            ushort hh = f2bf(e);
            hi[c] = (short)hh;
            lo[c] = (short)f2bf(e - bf2f(hh));
        }
        short* rp = hp3 + (size_t)i * 1536 + h * 64 + d * 4;
        *(short4*)(rp)        = make_short4(hi[0], hi[1], hi[2], hi[3]);
        *(short4*)(rp + 512)  = make_short4(lo[0], lo[1], lo[2], lo[3]);
        *(short4*)(rp + 1024) = make_short4(hi[0], hi[1], hi[2], hi[3]);
    }
}

// ---------------------------------------------------------------------------
// K6: sum gemm2 split-K partials -> Wh2, compute f1o/f2o. 4 rows/block.
// ---------------------------------------------------------------------------
__global__ __launch_bounds__(256) void f2sum(const float* __restrict__ part,
                                             const float* __restrict__ a,
                                             float* __restrict__ Wh2,
                                             float* __restrict__ f1o,
                                             float* __restrict__ f2o) {
    int wid = threadIdx.x >> 6, l = threadIdx.x & 63;
    int i = blockIdx.x * 4 + wid;
    size_t o = (size_t)i * 64 + l;
    const size_t S = (size_t)N_NODES * 64;
    float v = part[o] + part[o + S] + part[o + 2 * S] + part[o + 3 * S];
    Wh2[o] = v;
    float p1 = v * a[l], p2 = v * a[64 + l];
#pragma unroll
    for (int off = 32; off; off >>= 1) {
        p1 += __shfl_xor(p1, off);
        p2 += __shfl_xor(p2, off);
    }
    if (l == 0) { f1o[i] = p1; f2o[i] = p2; }
}

// ---------------------------------------------------------------------------
// K7: attn layer 2 + first GCN matmul (q-split float4); out pre-scaled dinv_i.
// ---------------------------------------------------------------------------
__global__ __launch_bounds__(256) void attn2_g0(const float* __restrict__ Wh2,
                                                const float* __restrict__ f1o,
                                                const float* __restrict__ f2o,
                                                const ushort* __restrict__ csr,
                                                const int* __restrict__ rowlen,
                                                const float* __restrict__ W0,
                                                const float* __restrict__ dinv,
                                                float* __restrict__ t0) {
    __shared__ float  w[4][MAXDEG];
    __shared__ ushort cl[4][MAXDEG];
    __shared__ float  hrow[4][64];
    int wid = threadIdx.x >> 6, lane = threadIdx.x & 63;
    int i = blockIdx.x * 4 + wid;
    int len = rowlen[i];
    const ushort* crow = csr + (size_t)i * MAXDEG;
    float myf1 = f1o[i];

    float ev[4]; int cv[4];
    float m = -1e30f;
#pragma unroll
    for (int c = 0; c < 4; c++) {
        int k = lane + c * 64;
        if (k < len) {
            int j = crow[k];
            float e = myf1 + f2o[j];
            e = e > 0.f ? e : ALPHA * e;
            ev[c] = e; cv[c] = j;
            m = fmaxf(m, e);
        }
    }
#pragma unroll
    for (int off = 32; off; off >>= 1) m = fmaxf(m, __shfl_xor(m, off));
    float s = 0.f;
#pragma unroll
    for (int c = 0; c < 4; c++) {
        int k = lane + c * 64;
        if (k < len) {
            float ex = __expf(ev[c] - m);
            s += ex;
            w[wid][k] = ex;
            cl[wid][k] = (ushort)cv[c];
        }
    }
#pragma unroll
    for (int off = 32; off; off >>= 1) s += __shfl_xor(s, off);
    float sinv = 1.0f / s;

    int len8 = (len + 7) & ~7;
    if (lane < len8 - len) {
        w[wid][len + lane] = 0.f;
        cl[wid][len + lane] = 0;
    }

    int q = lane >> 4, d = lane & 15;
    const float4* base = (const float4*)Wh2 + d;
    float ax0 = 0.f, ay0 = 0.f, az0 = 0.f, aw0 = 0.f;
    float ax1 = 0.f, ay1 = 0.f, az1 = 0.f, aw1 = 0.f;
    for (int k = 0; k < len8; k += 8) {
        int   j0 = cl[wid][k + q];
        int   j1 = cl[wid][k + 4 + q];
        float w0 = w[wid][k + q];
        float w1 = w[wid][k + 4 + q];
        float4 v0 = base[(size_t)j0 * 16];
        float4 v1 = base[(size_t)j1 * 16];
        ax0 += w0 * v0.x; ay0 += w0 * v0.y; az0 += w0 * v0.z; aw0 += w0 * v0.w;
        ax1 += w1 * v1.x; ay1 += w1 * v1.y; az1 += w1 * v1.z; aw1 += w1 * v1.w;
    }
    float rx = ax0 + ax1, ry = ay0 + ay1, rz = az0 + az1, rw = aw0 + aw1;
#pragma unroll
    for (int off = 16; off <= 32; off <<= 1) {
        rx += __shfl_xor(rx, off);
        ry += __shfl_xor(ry, off);
        rz += __shfl_xor(rz, off);
        rw += __shfl_xor(rw, off);
    }
    if (lane < 16) {
        float4 r = make_float4(rx * sinv, ry * sinv, rz * sinv, rw * sinv);
        *(float4*)&hrow[wid][d * 4] = r;
    }

    // matmul: q-split over kk, lanes<16 end with cols d*4..d*4+3
    float ox = 0.f, oy = 0.f, oz = 0.f, ow = 0.f;
#pragma unroll
    for (int it = 0; it < 16; it++) {
        int kk = q * 16 + it;
        float hv = hrow[wid][kk];
        float4 wv = *(const float4*)(W0 + kk * 64 + d * 4);
        ox += hv * wv.x; oy += hv * wv.y; oz += hv * wv.z; ow += hv * wv.w;
    }
#pragma unroll
    for (int off = 16; off <= 32; off <<= 1) {
        ox += __shfl_xor(ox, off);
        oy += __shfl_xor(oy, off);
        oz += __shfl_xor(oz, off);
        ow += __shfl_xor(ow, off);
    }
    if (lane < 16) {
        float di = dinv[i];
        *(float4*)(t0 + (size_t)i * 64 + d * 4) =
            make_float4(ox * di, oy * di, oz * di, ow * di);
    }
}

// ---------------------------------------------------------------------------
// K8: GCN step: h = relu(dinv_i * sum t'_j); out = dinv_i * (h @ W).
// q-split float4 gather + matmul.
// ---------------------------------------------------------------------------
__global__ __launch_bounds__(256) void spmv_gemm(const float* __restrict__ t,
                                                 const ushort* __restrict__ csr,
                                                 const int* __restrict__ rowlen,
                                                 const float* __restrict__ W,
                                                 const float* __restrict__ dinv,
                                                 float* __restrict__ out) {
    __shared__ float hrow[4][64];
    int wid = threadIdx.x >> 6, lane = threadIdx.x & 63;
    int i = blockIdx.x * 4 + wid;
    int len = rowlen[i];
    const ushort* ci = csr + (size_t)i * MAXDEG;
    int q = lane >> 4, d = lane & 15;
    const float4* base = (const float4*)t + d;
    int len8 = (len + 7) & ~7;
    float ax0 = 0.f, ay0 = 0.f, az0 = 0.f, aw0 = 0.f;
    float ax1 = 0.f, ay1 = 0.f, az1 = 0.f, aw1 = 0.f;
    for (int k = 0; k < len8; k += 8) {
        int k0 = k + q, k1 = k + 4 + q;
        float m0 = k0 < len ? 1.f : 0.f;
        float m1 = k1 < len ? 1.f : 0.f;
        int j0 = ci[k0 < len ? k0 : 0];
        int j1 = ci[k1 < len ? k1 : 0];
        float4 v0 = base[(size_t)j0 * 16];
        float4 v1 = base[(size_t)j1 * 16];
        ax0 += m0 * v0.x; ay0 += m0 * v0.y; az0 += m0 * v0.z; aw0 += m0 * v0.w;
        ax1 += m1 * v1.x; ay1 += m1 * v1.y; az1 += m1 * v1.z; aw1 += m1 * v1.w;
    }
    float rx = ax0 + ax1, ry = ay0 + ay1, rz = az0 + az1, rw = aw0 + aw1;
#pragma unroll
    for (int off = 16; off <= 32; off <<= 1) {
        rx += __shfl_xor(rx, off);
        ry += __shfl_xor(ry, off);
        rz += __shfl_xor(rz, off);
        rw += __shfl_xor(rw, off);
    }
    float di = dinv[i];
    if (lane < 16) {
        float4 r = make_float4(fmaxf(rx * di, 0.f), fmaxf(ry * di, 0.f),
                               fmaxf(rz * di, 0.f), fmaxf(rw * di, 0.f));
        *(float4*)&hrow[wid][d * 4] = r;
    }

    float ox = 0.f, oy = 0.f, oz = 0.f, ow = 0.f;
#pragma unroll
    for (int it = 0; it < 16; it++) {
        int kk = q * 16 + it;
        float hv = hrow[wid][kk];
        float4 wv = *(const float4*)(W + kk * 64 + d * 4);
        ox += hv * wv.x; oy += hv * wv.y; oz += hv * wv.z; ow += hv * wv.w;
    }
#pragma unroll
    for (int off = 16; off <= 32; off <<= 1) {
        ox += __shfl_xor(ox, off);
        oy += __shfl_xor(oy, off);
        oz += __shfl_xor(oz, off);
        ow += __shfl_xor(ow, off);
    }
    if (lane < 16)
        *(float4*)(out + (size_t)i * 64 + d * 4) =
            make_float4(ox * di, oy * di, oz * di, ow * di);
}

// ---------------------------------------------------------------------------
// K9: final GCN step into classifier (q-split gather; 64x8 matmul).
// ---------------------------------------------------------------------------
__global__ __launch_bounds__(256) void spmv_cls(const float* __restrict__ t,
                                                const ushort* __restrict__ csr,
                                                const int* __restrict__ rowlen,
                                                const float* __restrict__ Wc,
                                                const float* __restrict__ dinv,
                                                float* __restrict__ t8) {
    __shared__ float hrow[4][64];
    int wid = threadIdx.x >> 6, lane = threadIdx.x & 63;
    int i = blockIdx.x * 4 + wid;
    int len = rowlen[i];
    const ushort* ci = csr + (size_t)i * MAXDEG;
    int q = lane >> 4, d = lane & 15;
    const float4* base = (const float4*)t + d;
    int len8 = (len + 7) & ~7;
    float ax0 = 0.f, ay0 = 0.f, az0 = 0.f, aw0 = 0.f;
    float ax1 = 0.f, ay1 = 0.f, az1 = 0.f, aw1 = 0.f;
    for (int k = 0; k < len8; k += 8) {
        int k0 = k + q, k1 = k + 4 + q;
        float m0 = k0 < len ? 1.f : 0.f;
        float m1 = k1 < len ? 1.f : 0.f;
        int j0 = ci[k0 < len ? k0 : 0];
        int j1 = ci[k1 < len ? k1 : 0];
        float4 v0 = base[(size_t)j0 * 16];
        float4 v1 = base[(size_t)j1 * 16];
        ax0 += m0 * v0.x; ay0 += m0 * v0.y; az0 += m0 * v0.z; aw0 += m0 * v0.w;
        ax1 += m1 * v1.x; ay1 += m1 * v1.y; az1 += m1 * v1.z; aw1 += m1 * v1.w;
    }
    float rx = ax0 + ax1, ry = ay0 + ay1, rz = az0 + az1, rw = aw0 + aw1;
#pragma unroll
    for (int off = 16; off <= 32; off <<= 1) {
        rx += __shfl_xor(rx, off);
        ry += __shfl_xor(ry, off);
        rz += __shfl_xor(rz, off);
        rw += __shfl_xor(rw, off);
    }
    float di = dinv[i];
    if (lane < 16) {
        float4 r = make_float4(fmaxf(rx * di, 0.f), fmaxf(ry * di, 0.f),
                               fmaxf(rz * di, 0.f), fmaxf(rw * di, 0.f));
        *(float4*)&hrow[wid][d * 4] = r;
    }
    int col = lane & 7, k0s = (lane >> 3) * 8;
    float o = 0.f;
#pragma unroll
    for (int kk = 0; kk < 8; kk++) o += hrow[wid][k0s + kk] * Wc[(k0s + kk) * 8 + col];
    o += __shfl_down(o, 32);
    o += __shfl_down(o, 16);
    o += __shfl_down(o, 8);
    if (lane < 8) t8[(size_t)i * 8 + lane] = o * di;
}

// ---------------------------------------------------------------------------
// K10: final propagation on pre-scaled t8': out_i = dinv_i * sum t8'_j.
// ---------------------------------------------------------------------------
__global__ __launch_bounds__(256) void spmv8(const float* __restrict__ t8,
                                             const ushort* __restrict__ csr,
                                             const int* __restrict__ rowlen,
                                             const float* __restrict__ dinv,
                                             float* __restrict__ out) {
    int wid = threadIdx.x >> 6, lane = threadIdx.x & 63;
    int i = blockIdx.x * 4 + wid;
    int len = rowlen[i];
    const ushort* ci = csr + (size_t)i * MAXDEG;
    int col = lane & 7, chunk = lane >> 3;
    float acc = 0.f;
    for (int k = chunk; k < len; k += 8)
        acc += t8[(size_t)ci[k] * 8 + col];
    acc += __shfl_down(acc, 32);
    acc += __shfl_down(acc, 16);
    acc += __shfl_down(acc, 8);
    if (lane < 8) out[(size_t)i * 8 + lane] = acc * dinv[i];
}

// ---------------------------------------------------------------------------
extern "C" void kernel_launch(void* const* d_in, const int* in_sizes, int n_in,
                              void* d_out, int out_size, void* d_ws, size_t ws_size,
                              hipStream_t stream) {
    const float* x       = (const float*)d_in[0];
    const int*   adj     = (const int*)d_in[1];
    const float* W_heads = (const float*)d_in[2];
    const float* a_heads = (const float*)d_in[3];
    const float* W_out   = (const float*)d_in[4];
    const float* a_out   = (const float*)d_in[5];
    const float* W_gcn   = (const float*)d_in[6];
    const float* W_cls   = (const float*)d_in[7];
    float* outp = (float*)d_out;

    char* p = (char*)d_ws;
    short*  x3     = (short*)p;  p += (size_t)N_NODES * 3072 * 2;     // 25.2 MB
    short*  W3     = (short*)p;  p += (size_t)512 * 3072 * 2;         // 3.1 MB
    short*  W23    = (short*)p;  p += (size_t)64 * 1536 * 2;
    float*  Whh    = (float*)p;  p += (size_t)NHEADS * N_NODES * 64 * 4;  // 8 MB
    float*  f1h    = (float*)p;  p += (size_t)NHEADS * N_NODES * 4;
    float*  f2h    = (float*)p;  p += (size_t)NHEADS * N_NODES * 4;
    float*  Wh2    = (float*)p;  p += (size_t)N_NODES * 64 * 4;
    float*  f1o    = (float*)p;  p += (size_t)N_NODES * 4;
    float*  f2o    = (float*)p;  p += (size_t)N_NODES * 4;
    float*  tA     = (float*)p;  p += (size_t)N_NODES * 64 * 4;
    float*  tB     = (float*)p;  p += (size_t)N_NODES * 64 * 4;
    float*  t8     = (float*)p;  p += (size_t)N_NODES * 8 * 4;
    float*  dinv   = (float*)p;  p += (size_t)N_NODES * 4;
    int*    rowlen = (int*)p;    p += (size_t)N_NODES * 4;
    ushort* csr    = (ushort*)p; p += (size_t)N_NODES * MAXDEG * 2;   // 2 MB

    short* hp3  = x3;
    float* part = (float*)((char*)x3 + (16u << 20));

    build_csr<<<N_NODES, 64, 0, stream>>>(adj, csr, rowlen, dinv);

    prep<<<4096 + 128 + 8, 256, 0, stream>>>(x, W_heads, W_out, x3, W3, W23);

    gemm_mfma<<<256, 256, 0, stream>>>(x3, W3, Whh, 3072, 512, 3072, 0, 1, 1);

    compute_f1<<<N_NODES, 256, 0, stream>>>(Whh, a_heads, f1h, f2h);

    attn1<<<N_NODES * NHEADS / 4, 256, 0, stream>>>(Whh, f1h, f2h, csr, rowlen, hp3);

    gemm_mfma<<<dim3(N_NODES / GBM, 1, 4), 256, 0, stream>>>(
        hp3, W23, part, 1536, 64, 384, N_NODES * 64, 0, 0);

    f2sum<<<N_NODES / 4, 256, 0, stream>>>(part, a_out, Wh2, f1o, f2o);

    attn2_g0<<<N_NODES / 4, 256, 0, stream>>>(Wh2, f1o, f2o, csr, rowlen, W_gcn, dinv, tA);

    spmv_gemm<<<N_NODES / 4, 256, 0, stream>>>(tA, csr, rowlen, W_gcn + 4096, dinv, tB);
    spmv_gemm<<<N_NODES / 4, 256, 0, stream>>>(tB, csr, rowlen, W_gcn + 8192, dinv, tA);

    spmv_cls<<<N_NODES / 4, 256, 0, stream>>>(tA, csr, rowlen, W_cls, dinv, t8);
    spmv8<<<N_NODES / 4, 256, 0, stream>>>(t8, csr, rowlen, dinv, outp);
}

// Round 6
// 244.075 us; speedup vs baseline: 1.8422x; 1.0556x over previous
//
#include <hip/hip_runtime.h>
#include <hip/hip_bf16.h>
#include <math.h>

#define N_NODES 4096
#define NFEAT   1024
#define NHEADS  8
#define ALPHA   0.1f
#define MAXDEG  256

typedef short short8 __attribute__((ext_vector_type(8)));
typedef float f32x4  __attribute__((ext_vector_type(4)));

__device__ __forceinline__ ushort f2bf(float f) {
    uint b = __float_as_uint(f);
    b += 0x7FFFu + ((b >> 16) & 1u);            // RNE
    return (ushort)(b >> 16);
}
__device__ __forceinline__ float bf2f(ushort u) {
    return __uint_as_float(((uint)u) << 16);
}

// ---------------------------------------------------------------------------
// K1: merged prep. Blocks [0,4096): x -> x3 bf16 [hi|lo|hi].
// [4096,4224): W_heads transpose/split. [4224,4232): W_out.
// [4232,5256): build CSR (ushort) + dinv, 4 rows/block (one per wave).
// ---------------------------------------------------------------------------
__global__ __launch_bounds__(256) void prep_all(const float* __restrict__ x,
                                                const int* __restrict__ adj,
                                                const float* __restrict__ Whd,
                                                const float* __restrict__ Wo,
                                                short* __restrict__ x3,
                                                short* __restrict__ W3,
                                                short* __restrict__ W23,
                                                ushort* __restrict__ csr,
                                                int* __restrict__ rowlen,
                                                float* __restrict__ dinv) {
    __shared__ float tile[64][65];
    int b = blockIdx.x, t = threadIdx.x;
    if (b < 4096) {
        size_t idx = ((size_t)b * 256 + t) * 4;
        int row = (int)(idx >> 10);
        int col = (int)(idx & 1023);
        float4 v = *(const float4*)(x + idx);
        ushort h0 = f2bf(v.x), h1 = f2bf(v.y), h2 = f2bf(v.z), h3 = f2bf(v.w);
        short4 h = make_short4((short)h0, (short)h1, (short)h2, (short)h3);
        short4 l = make_short4((short)f2bf(v.x - bf2f(h0)), (short)f2bf(v.y - bf2f(h1)),
                               (short)f2bf(v.z - bf2f(h2)), (short)f2bf(v.w - bf2f(h3)));
        short* rp = x3 + (size_t)row * 3072 + col;
        *(short4*)(rp)        = h;
        *(short4*)(rp + 1024) = l;
        *(short4*)(rp + 2048) = h;
        return;
    }
    if (b < 4232) {
        const float* W; short* B3; int K, head, kb;
        if (b < 4224) { int id = b - 4096; W = Whd; B3 = W3;  K = 1024; head = id >> 4; kb = id & 15; }
        else          { int id = b - 4224; W = Wo;  B3 = W23; K = 512;  head = 0;       kb = id; }
        int k0 = kb * 64;
        const float* src = W + (size_t)head * K * 64 + (size_t)k0 * 64;
#pragma unroll
        for (int i = 0; i < 16; i++) {
            int lin = t + i * 256;
            int kk = lin >> 6, nn = lin & 63;
            tile[nn][kk] = src[kk * 64 + nn];
        }
        __syncthreads();
#pragma unroll
        for (int i = 0; i < 16; i++) {
            int lin = t + i * 256;
            int nn = lin >> 6, kk = lin & 63;
            float v = tile[nn][kk];
            ushort h = f2bf(v);
            ushort l = f2bf(v - bf2f(h));
            short* rp = B3 + (size_t)(head * 64 + nn) * (3 * (size_t)K) + k0 + kk;
            rp[0]     = (short)h;
            rp[K]     = (short)h;
            rp[2 * K] = (short)l;
        }
        return;
    }
    // CSR build: one row per wave
    int wid = t >> 6, lane = t & 63;
    int row = (b - 4232) * 4 + wid;
    const int4* arow = (const int4*)(adj + (size_t)row * N_NODES);
    unsigned long long pre = (1ull << lane) - 1ull;
    int count = 0;
    ushort* crow = csr + (size_t)row * MAXDEG;
    for (int blk = 0; blk < N_NODES / 256; blk++) {
        int4 v = arow[blk * 64 + lane];
        unsigned long long m0 = __ballot(v.x != 0);
        unsigned long long m1 = __ballot(v.y != 0);
        unsigned long long m2 = __ballot(v.z != 0);
        unsigned long long m3 = __ballot(v.w != 0);
        int pos = count + __popcll(m0 & pre) + __popcll(m1 & pre)
                        + __popcll(m2 & pre) + __popcll(m3 & pre);
        int base = blk * 256 + lane * 4;
        if (v.x) { if (pos < MAXDEG) crow[pos] = (ushort)base;       pos++; }
        if (v.y) { if (pos < MAXDEG) crow[pos] = (ushort)(base + 1); pos++; }
        if (v.z) { if (pos < MAXDEG) crow[pos] = (ushort)(base + 2); pos++; }
        if (v.w) { if (pos < MAXDEG) crow[pos] = (ushort)(base + 3); pos++; }
        count += __popcll(m0) + __popcll(m1) + __popcll(m2) + __popcll(m3);
    }
    if (lane == 0) {
        rowlen[row] = count < MAXDEG ? count : MAXDEG;
        dinv[row] = 1.0f / sqrtf((float)count);
    }
}

// ---------------------------------------------------------------------------
// K2: bf16 MFMA GEMM over concat-K.  C = A'[M][Kp] @ B'[N][Kp]^T.
// Tile 64x64, BK=64, 4 waves (2x2), wave tile 32x32. 37 KB LDS, double buf.
// headmajor: write C to Whh[head][row][64].  aH != null: fused f1/f2 epilogue
// (valid because GBN==64 => one col-tile == one head).
// ---------------------------------------------------------------------------
#define GBM 64
#define GBN 64
#define GBK 64
#define LDK 72

__global__ __launch_bounds__(256, 2) void gemm_mfma(const short* __restrict__ A,
                                                    const short* __restrict__ B,
                                                    float* __restrict__ C,
                                                    int Kp, int kChunk, int cPartStride,
                                                    int swz, int headmajor,
                                                    const float* __restrict__ aH,
                                                    float* __restrict__ f1h,
                                                    float* __restrict__ f2h) {
    __shared__ __align__(16) short As[2][GBM * LDK];
    __shared__ __align__(16) short Bs[2][GBN * LDK];

    int tid = threadIdx.x, lane = tid & 63, wid = tid >> 6;
    int wr = wid >> 1, wc = wid & 1;
    int bx, by;
    if (swz) {          // 512 blocks: XCD x gets bx in [x*8,x*8+8), by-inner
        int lin = blockIdx.x;
        bx = (lin & 7) * 8 + (lin >> 6);
        by = (lin >> 3) & 7;
    } else {
        bx = blockIdx.x; by = blockIdx.y;
    }
    int row0 = bx * GBM, col0 = by * GBN;
    int kbase = blockIdx.z * kChunk;
    C += (size_t)blockIdx.z * cPartStride;

    int aRow[2], aKc[2], bRow[2], bKc[2];
#pragma unroll
    for (int c = 0; c < 2; c++) {
        int lin = tid + c * 256;
        aRow[c] = lin >> 3; aKc[c] = (lin & 7) * 8;
        bRow[c] = lin >> 3; bKc[c] = (lin & 7) * 8;
    }

    short8 rA[2], rB[2];
    auto LOAD = [&](int k0) {
#pragma unroll
        for (int c = 0; c < 2; c++) {
            rA[c] = *(const short8*)(A + (size_t)(row0 + aRow[c]) * Kp + kbase + k0 + aKc[c]);
            rB[c] = *(const short8*)(B + (size_t)(col0 + bRow[c]) * Kp + kbase + k0 + bKc[c]);
        }
    };
    auto WRITE = [&](int buf) {
#pragma unroll
        for (int c = 0; c < 2; c++) {
            *(short8*)&As[buf][aRow[c] * LDK + aKc[c]] = rA[c];
            *(short8*)&Bs[buf][bRow[c] * LDK + bKc[c]] = rB[c];
        }
    };

    f32x4 acc[2][2];
#pragma unroll
    for (int m = 0; m < 2; m++)
#pragma unroll
        for (int n = 0; n < 2; n++) acc[m][n] = (f32x4){0.f, 0.f, 0.f, 0.f};

    LOAD(0);
    WRITE(0);
    __syncthreads();

    int nt = kChunk / GBK;
    for (int t = 0; t < nt; ++t) {
        int cur = t & 1;
        if (t + 1 < nt) LOAD((t + 1) * GBK);
#pragma unroll
        for (int ks = 0; ks < 2; ++ks) {
            short8 ah[2], bh[2];
            int ko = ks * 32 + (lane >> 4) * 8;
#pragma unroll
            for (int m = 0; m < 2; m++)
                ah[m] = *(const short8*)&As[cur][(wr * 32 + m * 16 + (lane & 15)) * LDK + ko];
#pragma unroll
            for (int n = 0; n < 2; n++)
                bh[n] = *(const short8*)&Bs[cur][(wc * 32 + n * 16 + (lane & 15)) * LDK + ko];
#pragma unroll
            for (int m = 0; m < 2; m++)
#pragma unroll
                for (int n = 0; n < 2; n++)
                    acc[m][n] = __builtin_amdgcn_mfma_f32_16x16x32_bf16(ah[m], bh[n], acc[m][n], 0, 0, 0);
        }
        if (t + 1 < nt) WRITE(cur ^ 1);
        __syncthreads();
    }

#pragma unroll
    for (int m = 0; m < 2; m++)
#pragma unroll
        for (int n = 0; n < 2; n++)
#pragma unroll
            for (int r = 0; r < 4; r++) {
                int rr = row0 + wr * 32 + m * 16 + (lane >> 4) * 4 + r;
                int cc = col0 + wc * 32 + n * 16 + (lane & 15);
                if (headmajor)
                    C[(size_t)(cc >> 6) * (N_NODES * 64) + (size_t)rr * 64 + (cc & 63)] = acc[m][n][r];
                else
                    C[(size_t)rr * 64 + cc] = acc[m][n][r];
            }

    if (aH) {   // fused f1/f2: head == by (GBN==64)
        __shared__ float f1p[2][64], f2p[2][64];
        const float* ahp = aH + by * 128;
        int cl = lane & 15;
        float a1x = ahp[wc * 32 + cl],      a1y = ahp[wc * 32 + 16 + cl];
        float a2x = ahp[64 + wc * 32 + cl], a2y = ahp[64 + wc * 32 + 16 + cl];
#pragma unroll
        for (int m = 0; m < 2; m++)
#pragma unroll
            for (int r = 0; r < 4; r++) {
                float s1 = acc[m][0][r] * a1x + acc[m][1][r] * a1y;
                float s2 = acc[m][0][r] * a2x + acc[m][1][r] * a2y;
#pragma unroll
                for (int off = 1; off < 16; off <<= 1) {
                    s1 += __shfl_xor(s1, off);
                    s2 += __shfl_xor(s2, off);
                }
                if ((lane & 15) == 0) {
                    int rl = wr * 32 + m * 16 + (lane >> 4) * 4 + r;
                    f1p[wc][rl] = s1;
                    f2p[wc][rl] = s2;
                }
            }
        __syncthreads();
        if (tid < 64) {
            f1h[(size_t)by * N_NODES + row0 + tid] = f1p[0][tid] + f1p[1][tid];
            f2h[(size_t)by * N_NODES + row0 + tid] = f2p[0][tid] + f2p[1][tid];
        }
    }
}

// ---------------------------------------------------------------------------
// K3: attn layer 1. Wave per (row, head); head = blockIdx&7 (XCD pinning).
// Gather: 16 neighbors/iter, 4 float4 loads in flight per lane.
// ---------------------------------------------------------------------------
__global__ __launch_bounds__(256, 4) void attn1(const float* __restrict__ Whh,
                                                const float* __restrict__ f1h,
                                                const float* __restrict__ f2h,
                                                const ushort* __restrict__ csr,
                                                const int* __restrict__ rowlen,
                                                short* __restrict__ hp3) {
    __shared__ float  w[4][MAXDEG];
    __shared__ ushort cols[4][MAXDEG];
    int lin = blockIdx.x;
    int h = lin & 7;
    int rq = lin >> 3;
    int wid = threadIdx.x >> 6, lane = threadIdx.x & 63;
    int i = rq * 4 + wid;
    int len = rowlen[i];
    const ushort* crow = csr + (size_t)i * MAXDEG;
    const float* f2p = f2h + (size_t)h * N_NODES;
    float f1v = f1h[(size_t)h * N_NODES + i];

    float ev[4]; int cv[4];
    float m = -1e30f;
#pragma unroll
    for (int c = 0; c < 4; c++) {
        int k = lane + c * 64;
        if (k < len) {
            int j = crow[k];
            float e = f1v + f2p[j];
            e = e > 0.f ? e : ALPHA * e;
            ev[c] = e; cv[c] = j;
            m = fmaxf(m, e);
        }
    }
#pragma unroll
    for (int off = 32; off; off >>= 1) m = fmaxf(m, __shfl_xor(m, off));
    float s = 0.f;
#pragma unroll
    for (int c = 0; c < 4; c++) {
        int k = lane + c * 64;
        if (k < len) {
            float ex = __expf(ev[c] - m);
            s += ex;
            w[wid][k] = ex;
            cols[wid][k] = (ushort)cv[c];
        }
    }
#pragma unroll
    for (int off = 32; off; off >>= 1) s += __shfl_xor(s, off);
    float sinv = 1.0f / s;

    int len16 = (len + 15) & ~15;
    if (lane < len16 - len) {           // zero-pad (<=15 entries)
        w[wid][len + lane] = 0.f;
        cols[wid][len + lane] = 0;
    }

    int q = lane >> 4, d = lane & 15;
    const float4* base = (const float4*)(Whh + (size_t)h * (N_NODES * 64)) + d;
    f32x4 A0 = {0.f,0.f,0.f,0.f}, A1 = A0, A2 = A0, A3 = A0;
    for (int k = 0; k < len16; k += 16) {
        int   j0 = cols[wid][k + q];       float w0 = w[wid][k + q];
        int   j1 = cols[wid][k + 4 + q];   float w1 = w[wid][k + 4 + q];
        int   j2 = cols[wid][k + 8 + q];   float w2 = w[wid][k + 8 + q];
        int   j3 = cols[wid][k + 12 + q];  float w3 = w[wid][k + 12 + q];
        float4 v0 = base[(size_t)j0 * 16];
        float4 v1 = base[(size_t)j1 * 16];
        float4 v2 = base[(size_t)j2 * 16];
        float4 v3 = base[(size_t)j3 * 16];
        A0[0] += w0 * v0.x; A0[1] += w0 * v0.y; A0[2] += w0 * v0.z; A0[3] += w0 * v0.w;
        A1[0] += w1 * v1.x; A1[1] += w1 * v1.y; A1[2] += w1 * v1.z; A1[3] += w1 * v1.w;
        A2[0] += w2 * v2.x; A2[1] += w2 * v2.y; A2[2] += w2 * v2.z; A2[3] += w2 * v2.w;
        A3[0] += w3 * v3.x; A3[1] += w3 * v3.y; A3[2] += w3 * v3.z; A3[3] += w3 * v3.w;
    }
    float rx = (A0[0] + A1[0]) + (A2[0] + A3[0]);
    float ry = (A0[1] + A1[1]) + (A2[1] + A3[1]);
    float rz = (A0[2] + A1[2]) + (A2[2] + A3[2]);
    float rw = (A0[3] + A1[3]) + (A2[3] + A3[3]);
#pragma unroll
    for (int off = 16; off <= 32; off <<= 1) {
        rx += __shfl_xor(rx, off);
        ry += __shfl_xor(ry, off);
        rz += __shfl_xor(rz, off);
        rw += __shfl_xor(rw, off);
    }
    if (lane < 16) {
        float v[4] = {rx * sinv, ry * sinv, rz * sinv, rw * sinv};
        short hi[4], lo[4];
#pragma unroll
        for (int c = 0; c < 4; c++) {
            float e = v[c] > 0.f ? v[c] : __expf(v[c]) - 1.f;   // ELU
            ushort hh = f2bf(e);
            hi[c] = (short)hh;
            lo[c] = (short)f2bf(e - bf2f(hh));
        }
        short* rp = hp3 + (size_t)i * 1536 + h * 64 + d * 4;
        *(short4*)(rp)        = make_short4(hi[0], hi[1], hi[2], hi[3]);
        *(short4*)(rp + 512)  = make_short4(lo[0], lo[1], lo[2], lo[3]);
        *(short4*)(rp + 1024) = make_short4(hi[0], hi[1], hi[2], hi[3]);
    }
}

// ---------------------------------------------------------------------------
// K4: sum gemm2 split-K partials -> Wh2, compute f1o/f2o. 4 rows/block.
// ---------------------------------------------------------------------------
__global__ __launch_bounds__(256) void f2sum(const float* __restrict__ part,
                                             const float* __restrict__ a,
                                             float* __restrict__ Wh2,
                                             float* __restrict__ f1o,
                                             float* __restrict__ f2o) {
    int wid = threadIdx.x >> 6, l = threadIdx.x & 63;
    int i = blockIdx.x * 4 + wid;
    size_t o = (size_t)i * 64 + l;
    const size_t S = (size_t)N_NODES * 64;
    float v = part[o] + part[o + S] + part[o + 2 * S] + part[o + 3 * S];
    Wh2[o] = v;
    float p1 = v * a[l], p2 = v * a[64 + l];
#pragma unroll
    for (int off = 32; off; off >>= 1) {
        p1 += __shfl_xor(p1, off);
        p2 += __shfl_xor(p2, off);
    }
    if (l == 0) { f1o[i] = p1; f2o[i] = p2; }
}

// ---------------------------------------------------------------------------
// K5: attn layer 2 + first GCN matmul; out pre-scaled by dinv_i. 4-deep ILP.
// ---------------------------------------------------------------------------
__global__ __launch_bounds__(256, 4) void attn2_g0(const float* __restrict__ Wh2,
                                                   const float* __restrict__ f1o,
                                                   const float* __restrict__ f2o,
                                                   const ushort* __restrict__ csr,
                                                   const int* __restrict__ rowlen,
                                                   const float* __restrict__ W0,
                                                   const float* __restrict__ dinv,
                                                   float* __restrict__ t0) {
    __shared__ float  w[4][MAXDEG];
    __shared__ ushort cl[4][MAXDEG];
    __shared__ float  hrow[4][64];
    int wid = threadIdx.x >> 6, lane = threadIdx.x & 63;
    int i = blockIdx.x * 4 + wid;
    int len = rowlen[i];
    const ushort* crow = csr + (size_t)i * MAXDEG;
    float myf1 = f1o[i];

    float ev[4]; int cv[4];
    float m = -1e30f;
#pragma unroll
    for (int c = 0; c < 4; c++) {
        int k = lane + c * 64;
        if (k < len) {
            int j = crow[k];
            float e = myf1 + f2o[j];
            e = e > 0.f ? e : ALPHA * e;
            ev[c] = e; cv[c] = j;
            m = fmaxf(m, e);
        }
    }
#pragma unroll
    for (int off = 32; off; off >>= 1) m = fmaxf(m, __shfl_xor(m, off));
    float s = 0.f;
#pragma unroll
    for (int c = 0; c < 4; c++) {
        int k = lane + c * 64;
        if (k < len) {
            float ex = __expf(ev[c] - m);
            s += ex;
            w[wid][k] = ex;
            cl[wid][k] = (ushort)cv[c];
        }
    }
#pragma unroll
    for (int off = 32; off; off >>= 1) s += __shfl_xor(s, off);
    float sinv = 1.0f / s;

    int len16 = (len + 15) & ~15;
    if (lane < len16 - len) {
        w[wid][len + lane] = 0.f;
        cl[wid][len + lane] = 0;
    }

    int q = lane >> 4, d = lane & 15;
    const float4* base = (const float4*)Wh2 + d;
    f32x4 A0 = {0.f,0.f,0.f,0.f}, A1 = A0, A2 = A0, A3 = A0;
    for (int k = 0; k < len16; k += 16) {
        int   j0 = cl[wid][k + q];       float w0 = w[wid][k + q];
        int   j1 = cl[wid][k + 4 + q];   float w1 = w[wid][k + 4 + q];
        int   j2 = cl[wid][k + 8 + q];   float w2 = w[wid][k + 8 + q];
        int   j3 = cl[wid][k + 12 + q];  float w3 = w[wid][k + 12 + q];
        float4 v0 = base[(size_t)j0 * 16];
        float4 v1 = base[(size_t)j1 * 16];
        float4 v2 = base[(size_t)j2 * 16];
        float4 v3 = base[(size_t)j3 * 16];
        A0[0] += w0 * v0.x; A0[1] += w0 * v0.y; A0[2] += w0 * v0.z; A0[3] += w0 * v0.w;
        A1[0] += w1 * v1.x; A1[1] += w1 * v1.y; A1[2] += w1 * v1.z; A1[3] += w1 * v1.w;
        A2[0] += w2 * v2.x; A2[1] += w2 * v2.y; A2[2] += w2 * v2.z; A2[3] += w2 * v2.w;
        A3[0] += w3 * v3.x; A3[1] += w3 * v3.y; A3[2] += w3 * v3.z; A3[3] += w3 * v3.w;
    }
    float rx = (A0[0] + A1[0]) + (A2[0] + A3[0]);
    float ry = (A0[1] + A1[1]) + (A2[1] + A3[1]);
    float rz = (A0[2] + A1[2]) + (A2[2] + A3[2]);
    float rw = (A0[3] + A1[3]) + (A2[3] + A3[3]);
#pragma unroll
    for (int off = 16; off <= 32; off <<= 1) {
        rx += __shfl_xor(rx, off);
        ry += __shfl_xor(ry, off);
        rz += __shfl_xor(rz, off);
        rw += __shfl_xor(rw, off);
    }
    if (lane < 16) {
        float4 r = make_float4(rx * sinv, ry * sinv, rz * sinv, rw * sinv);
        *(float4*)&hrow[wid][d * 4] = r;
    }

    float ox = 0.f, oy = 0.f, oz = 0.f, ow = 0.f;
#pragma unroll
    for (int it = 0; it < 16; it++) {
        int kk = q * 16 + it;
        float hv = hrow[wid][kk];
        float4 wv = *(const float4*)(W0 + kk * 64 + d * 4);
        ox += hv * wv.x; oy += hv * wv.y; oz += hv * wv.z; ow += hv * wv.w;
    }
#pragma unroll
    for (int off = 16; off <= 32; off <<= 1) {
        ox += __shfl_xor(ox, off);
        oy += __shfl_xor(oy, off);
        oz += __shfl_xor(oz, off);
        ow += __shfl_xor(ow, off);
    }
    if (lane < 16) {
        float di = dinv[i];
        *(float4*)(t0 + (size_t)i * 64 + d * 4) =
            make_float4(ox * di, oy * di, oz * di, ow * di);
    }
}

// ---------------------------------------------------------------------------
// K6: GCN step: h = relu(dinv_i * sum t'_j); out = dinv_i * (h @ W). 4-deep.
// ---------------------------------------------------------------------------
__global__ __launch_bounds__(256, 4) void spmv_gemm(const float* __restrict__ t,
                                                    const ushort* __restrict__ csr,
                                                    const int* __restrict__ rowlen,
                                                    const float* __restrict__ W,
                                                    const float* __restrict__ dinv,
                                                    float* __restrict__ out) {
    __shared__ float hrow[4][64];
    int wid = threadIdx.x >> 6, lane = threadIdx.x & 63;
    int i = blockIdx.x * 4 + wid;
    int len = rowlen[i];
    const ushort* ci = csr + (size_t)i * MAXDEG;
    int q = lane >> 4, d = lane & 15;
    const float4* base = (const float4*)t + d;
    int len16 = (len + 15) & ~15;
    f32x4 A0 = {0.f,0.f,0.f,0.f}, A1 = A0, A2 = A0, A3 = A0;
    for (int k = 0; k < len16; k += 16) {
        int k0 = k + q, k1 = k + 4 + q, k2 = k + 8 + q, k3 = k + 12 + q;
        float m0 = k0 < len ? 1.f : 0.f;
        float m1 = k1 < len ? 1.f : 0.f;
        float m2 = k2 < len ? 1.f : 0.f;
        float m3 = k3 < len ? 1.f : 0.f;
        int j0 = ci[k0 < len ? k0 : 0];
        int j1 = ci[k1 < len ? k1 : 0];
        int j2 = ci[k2 < len ? k2 : 0];
        int j3 = ci[k3 < len ? k3 : 0];
        float4 v0 = base[(size_t)j0 * 16];
        float4 v1 = base[(size_t)j1 * 16];
        float4 v2 = base[(size_t)j2 * 16];
        float4 v3 = base[(size_t)j3 * 16];
        A0[0] += m0 * v0.x; A0[1] += m0 * v0.y; A0[2] += m0 * v0.z; A0[3] += m0 * v0.w;
        A1[0] += m1 * v1.x; A1[1] += m1 * v1.y; A1[2] += m1 * v1.z; A1[3] += m1 * v1.w;
        A2[0] += m2 * v2.x; A2[1] += m2 * v2.y; A2[2] += m2 * v2.z; A2[3] += m2 * v2.w;
        A3[0] += m3 * v3.x; A3[1] += m3 * v3.y; A3[2] += m3 * v3.z; A3[3] += m3 * v3.w;
    }
    float rx = (A0[0] + A1[0]) + (A2[0] + A3[0]);
    float ry = (A0[1] + A1[1]) + (A2[1] + A3[1]);
    float rz = (A0[2] + A1[2]) + (A2[2] + A3[2]);
    float rw = (A0[3] + A1[3]) + (A2[3] + A3[3]);
#pragma unroll
    for (int off = 16; off <= 32; off <<= 1) {
        rx += __shfl_xor(rx, off);
        ry += __shfl_xor(ry, off);
        rz += __shfl_xor(rz, off);
        rw += __shfl_xor(rw, off);
    }
    float di = dinv[i];
    if (lane < 16) {
        float4 r = make_float4(fmaxf(rx * di, 0.f), fmaxf(ry * di, 0.f),
                               fmaxf(rz * di, 0.f), fmaxf(rw * di, 0.f));
        *(float4*)&hrow[wid][d * 4] = r;
    }

    float ox = 0.f, oy = 0.f, oz = 0.f, ow = 0.f;
#pragma unroll
    for (int it = 0; it < 16; it++) {
        int kk = q * 16 + it;
        float hv = hrow[wid][kk];
        float4 wv = *(const float4*)(W + kk * 64 + d * 4);
        ox += hv * wv.x; oy += hv * wv.y; oz += hv * wv.z; ow += hv * wv.w;
    }
#pragma unroll
    for (int off = 16; off <= 32; off <<= 1) {
        ox += __shfl_xor(ox, off);
        oy += __shfl_xor(oy, off);
        oz += __shfl_xor(oz, off);
        ow += __shfl_xor(ow, off);
    }
    if (lane < 16)
        *(float4*)(out + (size_t)i * 64 + d * 4) =
            make_float4(ox * di, oy * di, oz * di, ow * di);
}

// ---------------------------------------------------------------------------
// K7: final GCN step into classifier. 4-deep gather; 64x8 matmul.
// ---------------------------------------------------------------------------
__global__ __launch_bounds__(256, 4) void spmv_cls(const float* __restrict__ t,
                                                   const ushort* __restrict__ csr,
                                                   const int* __restrict__ rowlen,
                                                   const float* __restrict__ Wc,
                                                   const float* __restrict__ dinv,
                                                   float* __restrict__ t8) {
    __shared__ float hrow[4][64];
    int wid = threadIdx.x >> 6, lane = threadIdx.x & 63;
    int i = blockIdx.x * 4 + wid;
    int len = rowlen[i];
    const ushort* ci = csr + (size_t)i * MAXDEG;
    int q = lane >> 4, d = lane & 15;
    const float4* base = (const float4*)t + d;
    int len16 = (len + 15) & ~15;
    f32x4 A0 = {0.f,0.f,0.f,0.f}, A1 = A0, A2 = A0, A3 = A0;
    for (int k = 0; k < len16; k += 16) {
        int k0 = k + q, k1 = k + 4 + q, k2 = k + 8 + q, k3 = k + 12 + q;
        float m0 = k0 < len ? 1.f : 0.f;
        float m1 = k1 < len ? 1.f : 0.f;
        float m2 = k2 < len ? 1.f : 0.f;
        float m3 = k3 < len ? 1.f : 0.f;
        int j0 = ci[k0 < len ? k0 : 0];
        int j1 = ci[k1 < len ? k1 : 0];
        int j2 = ci[k2 < len ? k2 : 0];
        int j3 = ci[k3 < len ? k3 : 0];
        float4 v0 = base[(size_t)j0 * 16];
        float4 v1 = base[(size_t)j1 * 16];
        float4 v2 = base[(size_t)j2 * 16];
        float4 v3 = base[(size_t)j3 * 16];
        A0[0] += m0 * v0.x; A0[1] += m0 * v0.y; A0[2] += m0 * v0.z; A0[3] += m0 * v0.w;
        A1[0] += m1 * v1.x; A1[1] += m1 * v1.y; A1[2] += m1 * v1.z; A1[3] += m1 * v1.w;
        A2[0] += m2 * v2.x; A2[1] += m2 * v2.y; A2[2] += m2 * v2.z; A2[3] += m2 * v2.w;
        A3[0] += m3 * v3.x; A3[1] += m3 * v3.y; A3[2] += m3 * v3.z; A3[3] += m3 * v3.w;
    }
    float rx = (A0[0] + A1[0]) + (A2[0] + A3[0]);
    float ry = (A0[1] + A1[1]) + (A2[1] + A3[1]);
    float rz = (A0[2] + A1[2]) + (A2[2] + A3[2]);
    float rw = (A0[3] + A1[3]) + (A2[3] + A3[3]);
#pragma unroll
    for (int off = 16; off <= 32; off <<= 1) {
        rx += __shfl_xor(rx, off);
        ry += __shfl_xor(ry, off);
        rz += __shfl_xor(rz, off);
        rw += __shfl_xor(rw, off);
    }
    float di = dinv[i];
    if (lane < 16) {
        float4 r = make_float4(fmaxf(rx * di, 0.f), fmaxf(ry * di, 0.f),
                               fmaxf(rz * di, 0.f), fmaxf(rw * di, 0.f));
        *(float4*)&hrow[wid][d * 4] = r;
    }
    int col = lane & 7, k0s = (lane >> 3) * 8;
    float o = 0.f;
#pragma unroll
    for (int kk = 0; kk < 8; kk++) o += hrow[wid][k0s + kk] * Wc[(k0s + kk) * 8 + col];
    o += __shfl_down(o, 32);
    o += __shfl_down(o, 16);
    o += __shfl_down(o, 8);
    if (lane < 8) t8[(size_t)i * 8 + lane] = o * di;
}

// ---------------------------------------------------------------------------
// K8: final propagation on pre-scaled t8': out_i = dinv_i * sum t8'_j.
// ---------------------------------------------------------------------------
__global__ __launch_bounds__(256) void spmv8(const float* __restrict__ t8,
                                             const ushort* __restrict__ csr,
                                             const int* __restrict__ rowlen,
                                             const float* __restrict__ dinv,
                                             float* __restrict__ out) {
    int wid = threadIdx.x >> 6, lane = threadIdx.x & 63;
    int i = blockIdx.x * 4 + wid;
    int len = rowlen[i];
    const ushort* ci = csr + (size_t)i * MAXDEG;
    int col = lane & 7, chunk = lane >> 3;
    float acc = 0.f;
    for (int k = chunk; k < len; k += 8)
        acc += t8[(size_t)ci[k] * 8 + col];
    acc += __shfl_down(acc, 32);
    acc += __shfl_down(acc, 16);
    acc += __shfl_down(acc, 8);
    if (lane < 8) out[(size_t)i * 8 + lane] = acc * dinv[i];
}

// ---------------------------------------------------------------------------
extern "C" void kernel_launch(void* const* d_in, const int* in_sizes, int n_in,
                              void* d_out, int out_size, void* d_ws, size_t ws_size,
                              hipStream_t stream) {
    const float* x       = (const float*)d_in[0];
    const int*   adj     = (const int*)d_in[1];
    const float* W_heads = (const float*)d_in[2];
    const float* a_heads = (const float*)d_in[3];
    const float* W_out   = (const float*)d_in[4];
    const float* a_out   = (const float*)d_in[5];
    const float* W_gcn   = (const float*)d_in[6];
    const float* W_cls   = (const float*)d_in[7];
    float* outp = (float*)d_out;

    char* p = (char*)d_ws;
    short*  x3     = (short*)p;  p += (size_t)N_NODES * 3072 * 2;     // 25.2 MB
    short*  W3     = (short*)p;  p += (size_t)512 * 3072 * 2;         // 3.1 MB
    short*  W23    = (short*)p;  p += (size_t)64 * 1536 * 2;
    float*  Whh    = (float*)p;  p += (size_t)NHEADS * N_NODES * 64 * 4;  // 8 MB
    float*  f1h    = (float*)p;  p += (size_t)NHEADS * N_NODES * 4;
    float*  f2h    = (float*)p;  p += (size_t)NHEADS * N_NODES * 4;
    float*  Wh2    = (float*)p;  p += (size_t)N_NODES * 64 * 4;
    float*  f1o    = (float*)p;  p += (size_t)N_NODES * 4;
    float*  f2o    = (float*)p;  p += (size_t)N_NODES * 4;
    float*  tA     = (float*)p;  p += (size_t)N_NODES * 64 * 4;
    float*  tB     = (float*)p;  p += (size_t)N_NODES * 64 * 4;
    float*  t8     = (float*)p;  p += (size_t)N_NODES * 8 * 4;
    float*  dinv   = (float*)p;  p += (size_t)N_NODES * 4;
    int*    rowlen = (int*)p;    p += (size_t)N_NODES * 4;
    ushort* csr    = (ushort*)p; p += (size_t)N_NODES * MAXDEG * 2;   // 2 MB

    short* hp3  = x3;
    float* part = (float*)((char*)x3 + (16u << 20));

    // K1: prep (splits) + CSR build in one launch
    prep_all<<<4096 + 128 + 8 + 1024, 256, 0, stream>>>(
        x, adj, W_heads, W_out, x3, W3, W23, csr, rowlen, dinv);

    // K2: gemm1 Whh = x' @ W' (head-major) + fused f1/f2 epilogue
    gemm_mfma<<<512, 256, 0, stream>>>(x3, W3, Whh, 3072, 3072, 0, 1, 1,
                                       a_heads, f1h, f2h);

    // K3: attn layer 1 (+ELU) -> hp3 concat-K [4096][1536]
    attn1<<<N_NODES * NHEADS / 4, 256, 0, stream>>>(Whh, f1h, f2h, csr, rowlen, hp3);

    // K4: gemm2 partials = hp' @ W2' (K'=1536, split-K=4 -> 256 blocks)
    gemm_mfma<<<dim3(N_NODES / GBM, 1, 4), 256, 0, stream>>>(
        hp3, W23, part, 1536, 384, N_NODES * 64, 0, 0, nullptr, nullptr, nullptr);

    // K5: partial sum + f1o/f2o
    f2sum<<<N_NODES / 4, 256, 0, stream>>>(part, a_out, Wh2, f1o, f2o);

    // K6: attn layer 2 + W_gcn[0]
    attn2_g0<<<N_NODES / 4, 256, 0, stream>>>(Wh2, f1o, f2o, csr, rowlen, W_gcn, dinv, tA);

    // K7-8: GCN blocks 1,2
    spmv_gemm<<<N_NODES / 4, 256, 0, stream>>>(tA, csr, rowlen, W_gcn + 4096, dinv, tB);
    spmv_gemm<<<N_NODES / 4, 256, 0, stream>>>(tB, csr, rowlen, W_gcn + 8192, dinv, tA);

    // K9-10: final block + classifier, last propagation
    spmv_cls<<<N_NODES / 4, 256, 0, stream>>>(tA, csr, rowlen, W_cls, dinv, t8);
    spmv8<<<N_NODES / 4, 256, 0, stream>>>(t8, csr, rowlen, dinv, outp);
}